// Round 21
// baseline (1492.108 us; speedup 1.0000x reference)
//
#include <hip/hip_runtime.h>

#define V_ 32000
#define D_ 1024
#define L_ 8
#define HQ_ 16
#define HKV_ 4
#define HD_ 64
#define H_ 2752
#define B_ 2
#define S_ 1024
#define BS_ 2048
#define WINDOW_ 256
#define PACK_ 11075584  // u16 elements per per-layer weight pack

typedef float f32x4 __attribute__((ext_vector_type(4)));
typedef short s16x8 __attribute__((ext_vector_type(8)));
typedef unsigned short u16;

__device__ __forceinline__ u16 f2b(float f) {
  union { float f; unsigned u; } a; a.f = f;
  return (u16)((a.u + 0x7fffu + ((a.u >> 16) & 1u)) >> 16);
}
__device__ __forceinline__ float b2f(u16 b) {
  union { unsigned u; float f; } a; a.u = ((unsigned)b) << 16; return a.f;
}

// async global->LDS, 16B per lane. LDS dest must be wave-uniform; CK-style casts.
__device__ __forceinline__ void gload_lds16(const void* g, void* l) {
  __builtin_amdgcn_global_load_lds(
      (const __attribute__((address_space(1))) void*)(unsigned long long)(uintptr_t)g,
      (__attribute__((address_space(3))) void*)(unsigned int)(uintptr_t)l,
      16, 0, 0);
}

// ---- 7-matrix transpose-convert body (dst row = src_col*mul + add) ----------
struct TMat { const float* src; u16* dst; int R, C, t0, mul, add; };
struct T7 { TMat m[7]; };

__device__ __forceinline__ void transpose_body(const T7& P, int tb,
                                               float (*tile)[33], int tid) {
  int mi = 0;
#pragma unroll
  for (int i = 1; i < 7; ++i) if (tb >= P.m[i].t0) mi = i;
  TMat mm = P.m[mi];
  int tl = tb - mm.t0;
  int ct = mm.C >> 5;
  int tr = tl / ct, tc = tl - tr * ct;
  int r0 = tr << 5, c0 = tc << 5;
  int tx = tid & 31, ty = tid >> 5;
#pragma unroll
  for (int j = 0; j < 4; ++j)
    tile[ty + j * 8][tx] = mm.src[(size_t)(r0 + ty + j * 8) * mm.C + c0 + tx];
  __syncthreads();
#pragma unroll
  for (int j = 0; j < 4; ++j)
    mm.dst[((size_t)(c0 + ty + j * 8) * mm.mul + mm.add) * mm.R + r0 + tx] =
        f2b(tile[tx][ty + j * 8]);
}

// ---------------- startup: emb cvt + rope table + embed + transpose(L0) -------
__global__ void k_init(const float* __restrict__ src, u16* __restrict__ dst,
                       float* __restrict__ cosT, float* __restrict__ sinT,
                       const int* __restrict__ idx, float* __restrict__ x, T7 P0) {
  int bid = blockIdx.x;
  if (bid < 32000) {  // cvt: 32000 blocks x 256 thr x float4 = V*D exactly
    long i = (long)bid * 256 + threadIdx.x;
    float4 v = ((const float4*)src)[i];
    ushort4 o; o.x = f2b(v.x); o.y = f2b(v.y); o.z = f2b(v.z); o.w = f2b(v.w);
    ((ushort4*)dst)[i] = o;
  } else if (bid < 32128) {  // ropetab: 128 blocks -> S*32 entries
    int i = (bid - 32000) * 256 + threadIdx.x;
    int s = i >> 5, d = i & 31;
    float inv = __expf(-((float)(2 * d) / (float)HD_) * logf(10000.0f));
    float f = (float)s * inv;
    cosT[i] = cosf(f); sinT[i] = sinf(f);
  } else if (bid < 34176) {  // embed: 2048 blocks
    int t = bid - 32128;
    int token = idx[t];
    const float4* s = (const float4*)(src + (size_t)token * D_);
    float4* d = (float4*)(x + (size_t)t * D_);
    d[threadIdx.x] = s[threadIdx.x];
  } else {  // transpose layer 0 -> pack 0: 10816 blocks
    __shared__ float tile[32][33];
    transpose_body(P0, bid - 34176, tile, threadIdx.x);
  }
}

// ---------------- rmsnorm (fp32 in) -> bf16 out ----------------
__global__ void k_rmsnorm(const float* __restrict__ x, const float* __restrict__ w,
                          u16* __restrict__ out) {
  int row = blockIdx.x, tid = threadIdx.x;
  float4 v = ((const float4*)(x + (size_t)row * D_))[tid];
  float ss = v.x * v.x + v.y * v.y + v.z * v.z + v.w * v.w;
#pragma unroll
  for (int m = 1; m < 64; m <<= 1) ss += __shfl_xor(ss, m, 64);
  __shared__ float red[4];
  if ((tid & 63) == 0) red[tid >> 6] = ss;
  __syncthreads();
  float tot = red[0] + red[1] + red[2] + red[3];
  float rs = rsqrtf(tot * (1.0f / D_) + 1e-6f);
  float4 wv = ((const float4*)w)[tid];
  ushort4 o;
  o.x = f2b(v.x * rs * wv.x); o.y = f2b(v.y * rs * wv.y);
  o.z = f2b(v.z * rs * wv.z); o.w = f2b(v.w * rs * wv.w);
  ((ushort4*)(out + (size_t)row * D_))[tid] = o;
}

// ---------------- fused rope (q,k) + V transpose; one launch/layer ------------
__global__ void k_ropev(const float* __restrict__ qkvf, const float* __restrict__ cosT,
                        const float* __restrict__ sinT, u16* __restrict__ qh,
                        u16* __restrict__ kh, u16* __restrict__ vth) {
  __shared__ float tile[32][65];
  int bid = blockIdx.x;
  int tid = threadIdx.x;
  if (bid < BS_) {  // RoPE: q + k head-major
    int t = bid;
    int b = t >> 10, s = t & (S_ - 1);
    const float* row = qkvf + (size_t)t * 1536;
    for (int p = tid; p < 512; p += 256) {           // q: 512 pairs
      int hh = p >> 5, d = p & 31;
      float x0 = row[hh * 64 + 2 * d], x1 = row[hh * 64 + 2 * d + 1];
      float c = cosT[s * 32 + d], sn = sinT[s * 32 + d];
      size_t o = ((size_t)(b * HQ_ + hh) * S_ + s) * HD_ + 2 * d;
      qh[o] = f2b(x0 * c - x1 * sn);
      qh[o + 1] = f2b(x0 * sn + x1 * c);
    }
    if (tid < 128) {                                  // k: 128 pairs
      int hh = tid >> 5, d = tid & 31;
      float x0 = row[1024 + hh * 64 + 2 * d], x1 = row[1024 + hh * 64 + 2 * d + 1];
      float c = cosT[s * 32 + d], sn = sinT[s * 32 + d];
      size_t o = ((size_t)(b * HKV_ + hh) * S_ + s) * HD_ + 2 * d;
      kh[o] = f2b(x0 * c - x1 * sn);
      kh[o + 1] = f2b(x0 * sn + x1 * c);
    }
  } else {  // V transpose -> vth [b][kvh][64][S]
    int v = bid - BS_;                // 0..255
    const int s0 = (v & 31) << 5, hh = (v >> 5) & 3, b = v >> 7;
    const int tx = tid & 63, ty = tid >> 6;  // load: 64 d x 4 s-rows
#pragma unroll
    for (int j = 0; j < 8; ++j) {
      int sl = j * 4 + ty;
      tile[sl][tx] = qkvf[(size_t)((b << 10) + s0 + sl) * 1536 + 1280 + hh * 64 + tx];
    }
    __syncthreads();
    const int sx = tid & 31, dr = tid >> 5;  // store: 32 s x 8 d-rows
#pragma unroll
    for (int j = 0; j < 8; ++j) {
      int d = j * 8 + dr;
      vth[((size_t)((b * HKV_ + hh) << 6) + d) * S_ + s0 + sx] = f2b(tile[sx][d]);
    }
  }
}

// ---- shared 128x128 GEMM body (depth-2, 3-buffer, counted vmcnt; r12-class) --
// bx = M-tile [0,16), by = N-tile, bz = split-K half. cpx = logical nwg/8 for
// the bijective XCD swizzle (MUST match the logical grid: 24 for (16,12),
// 16 for (16,8,2) -- r20 bug was hardcoding 16).
// EPI: 0 = f32 store, 4 = fp32 atomicAdd.
template <int EPI>
__device__ __forceinline__ void gemm128_body(const u16* __restrict__ A,
                                             const u16* __restrict__ BT,
                                             void* __restrict__ Cp, int kdepth,
                                             int lda, int ldc, int bx, int by, int bz,
                                             int cpx, u16 (*As)[4096], u16 (*Bs)[4096]) {
  const int tid = threadIdx.x;
  const int lane = tid & 63, wid = tid >> 6;
  const int lin = by * 16 + bx;
  const int swz = (lin & 7) * cpx + (lin >> 3);
  const int m0 = (swz & 15) << 7, n0 = (swz >> 4) << 7;
  const int wm = (wid >> 1) << 6, wn = (wid & 1) << 6;
  const int fr = lane & 15, fg = lane >> 4;

  f32x4 acc[4][4] = {};

  const int srow = (wid << 4) + (lane >> 2);
  const int scol = ((lane & 3) - ((lane >> 3) & 3)) & 3;
  const int kz = bz * kdepth;
  const u16* ga = A + (size_t)(m0 + srow) * lda + kz + (scol << 3);
  const u16* gb = BT + (size_t)(n0 + srow) * lda + kz + (scol << 3);
  const int cb = wid << 9;  // wave-uniform LDS chunk base (u16 units)

  auto stage = [&](int buf, int k0) {
    u16* la = &As[buf][cb];
    u16* lb = &Bs[buf][cb];
    gload_lds16(ga + k0, la);
    gload_lds16(ga + (size_t)64 * lda + k0, la + 2048);
    gload_lds16(gb + k0, lb);
    gload_lds16(gb + (size_t)64 * lda + k0, lb + 2048);
  };

  const int nk = kdepth >> 5;
  stage(0, 0);
  stage(1, 32);

  const int ab = (wid >> 1) << 2, bb = (wid & 1) << 2;  // 16-row block bases
  const int foff = (fr << 5) + ((((fg + (fr >> 1)) & 3)) << 3);
  int cur = 0;
  for (int t = 0; t < nk; ++t) {
    if (t + 2 < nk) {
      int nb = cur + 2; if (nb >= 3) nb -= 3;
      stage(nb, (t + 2) << 5);
      asm volatile("s_waitcnt vmcnt(8)" ::: "memory");   // tile t retired; t+1,t+2 in flight
    } else if (t + 2 == nk) {
      asm volatile("s_waitcnt vmcnt(4)" ::: "memory");
    } else {
      asm volatile("s_waitcnt vmcnt(0)" ::: "memory");
    }
    __builtin_amdgcn_s_barrier();  // all waves' tile-t writes visible
    s16x8 af[4], bq[4];
#pragma unroll
    for (int i = 0; i < 4; ++i) {
      af[i] = *(const s16x8*)(&As[cur][((ab + i) << 9) + foff]);
      bq[i] = *(const s16x8*)(&Bs[cur][((bb + i) << 9) + foff]);
    }
#pragma unroll
    for (int mi = 0; mi < 4; ++mi)
#pragma unroll
      for (int ni = 0; ni < 4; ++ni)
        acc[mi][ni] = __builtin_amdgcn_mfma_f32_16x16x32_bf16(af[mi], bq[ni], acc[mi][ni], 0, 0, 0);
    __builtin_amdgcn_s_barrier();  // reads of buf(t) done before t+3 overwrites
    if (++cur == 3) cur = 0;
  }

#pragma unroll
  for (int mi = 0; mi < 4; ++mi) {
#pragma unroll
    for (int ni = 0; ni < 4; ++ni) {
#pragma unroll
      for (int r = 0; r < 4; ++r) {
        int row = m0 + wm + mi * 16 + fg * 4 + r;
        int col = n0 + wn + ni * 16 + fr;
        size_t off = (size_t)row * ldc + col;
        float v = acc[mi][ni][r];
        if (EPI == 0) ((float*)Cp)[off] = v;
        else atomicAdd((float*)Cp + off, v);
      }
    }
  }
}

// ---------------- 128x128 GEMM kernel (3D grid; qkv f32-store + wo atomic) ----
template <int EPI>
__global__ __launch_bounds__(256) void k_gemm(const u16* __restrict__ A,
                                              const u16* __restrict__ BT,
                                              void* __restrict__ Cp, int kdepth,
                                              int lda, int ldc) {
  __shared__ u16 As[3][4096];
  __shared__ u16 Bs[3][4096];
  gemm128_body<EPI>(A, BT, Cp, kdepth, lda, ldc, blockIdx.x, blockIdx.y, blockIdx.z,
                    (gridDim.x * gridDim.y) >> 3, As, Bs);
}

// ---- fused: w2 split-K GEMM (256 blocks, 1/CU) + next layer's weight transpose
// blocks [0,256): gemm atomic epilogue (bz=bid>>7, by=(bid&127)>>4, bx=bid&15 --
// exact block set of the (16,8,2) 3D launch, logical cpx = 128/8 = 16).
// blocks >=256: transpose into the OTHER weight pack (double-buffered);
// fills the CUs the 256-block GEMM leaves idle.
__global__ __launch_bounds__(256) void k_gemmtr(const u16* __restrict__ A,
                                                const u16* __restrict__ BT,
                                                void* __restrict__ Cp, int kdepth,
                                                int lda, int ldc, T7 P) {
  __shared__ u16 As[3][4096];
  __shared__ u16 Bs[3][4096];
  int bid = blockIdx.x;
  if (bid >= 256) {  // transpose path (only present when grid > 256)
    __shared__ float tile[32][33];
    transpose_body(P, bid - 256, tile, threadIdx.x);
    return;
  }
  gemm128_body<4>(A, BT, Cp, kdepth, lda, ldc, bid & 15, (bid & 127) >> 4, bid >> 7,
                  16, As, Bs);
}

// ---------------- 256x128 bf16 MFMA GEMM (big-N: lm_head, h13) ----------------
// 512 threads / 8 waves (4M x 2N, 64x64 out each): 16 waves/CU = 4 waves/SIMD.
// Depth-2 3-buffer counted-vmcnt schedule (r12 verified best); 3 loads/wave/stage.
// EPI: 0 = f32 store, 3 = fused SwiGLU (interleaved W13 pack; even lanes write
// silu(h1)*h3 bf16 to g, ldc = 2752).
template <int EPI>
__global__ __launch_bounds__(512, 4) void k_gemm2(const u16* __restrict__ A,
                                                  const u16* __restrict__ BT,
                                                  void* __restrict__ Cp, int K, int ldc) {
  __shared__ u16 As[3][8192];  // [16 blocks16][512 u16] x 3
  __shared__ u16 Bs[3][4096];  // [8 blocks16]
  const int tid = threadIdx.x;
  const int lane = tid & 63, wid = tid >> 6;  // 8 waves
  const int lin = blockIdx.y * gridDim.x + blockIdx.x;  // gridDim.x == 8
  const int cpx = (gridDim.x * gridDim.y) >> 3;
  const int swz = (lin & 7) * cpx + (lin >> 3);
  const int m0 = (swz & 7) << 8, n0 = (swz >> 3) << 7;
  const int fr = lane & 15, fg = lane >> 4;

  f32x4 acc[4][4] = {};

  const int srow = lane >> 2;  // 0..15 within a 16-row block
  const int scol = ((lane & 3) - ((lane >> 3) & 3)) & 3;
  // wave w stages A rows [32w,32w+32) -> blocks 2w,2w+1 ; B rows [16w,16w+16) -> block w
  const u16* ga = A + (size_t)(m0 + (wid << 5) + srow) * K + (scol << 3);
  const u16* gb = BT + (size_t)(n0 + (wid << 4) + srow) * K + (scol << 3);
  const int cba = wid << 10;  // 2 blocks * 512 u16
  const int cbb = wid << 9;   // 1 block * 512 u16

  auto stage = [&](int buf, int k0) {
    gload_lds16(ga + k0, &As[buf][cba]);
    gload_lds16(ga + (size_t)16 * K + k0, &As[buf][cba + 512]);
    gload_lds16(gb + k0, &Bs[buf][cbb]);
  };

  const int nk = K >> 5;
  stage(0, 0);
  stage(1, 32);

  const int am = (wid >> 1) << 2;  // A block base: wave M-group * 4
  const int bn = (wid & 1) << 2;   // B block base: wave N-group * 4
  const int foff = (fr << 5) + ((((fg + (fr >> 1)) & 3)) << 3);
  int cur = 0;
  for (int t = 0; t < nk; ++t) {
    if (t + 2 < nk) {
      int nb = cur + 2; if (nb >= 3) nb -= 3;
      stage(nb, (t + 2) << 5);
      asm volatile("s_waitcnt vmcnt(6)" ::: "memory");  // tile t retired; t+1,t+2 in flight
    } else if (t + 2 == nk) {
      asm volatile("s_waitcnt vmcnt(3)" ::: "memory");
    } else {
      asm volatile("s_waitcnt vmcnt(0)" ::: "memory");
    }
    __builtin_amdgcn_s_barrier();
    s16x8 af[4], bq[4];
#pragma unroll
    for (int i = 0; i < 4; ++i) {
      af[i] = *(const s16x8*)(&As[cur][((am + i) << 9) + foff]);
      bq[i] = *(const s16x8*)(&Bs[cur][((bn + i) << 9) + foff]);
    }
#pragma unroll
    for (int mi = 0; mi < 4; ++mi)
#pragma unroll
      for (int ni = 0; ni < 4; ++ni)
        acc[mi][ni] = __builtin_amdgcn_mfma_f32_16x16x32_bf16(af[mi], bq[ni], acc[mi][ni], 0, 0, 0);
    __builtin_amdgcn_s_barrier();
    if (++cur == 3) cur = 0;
  }

#pragma unroll
  for (int mi = 0; mi < 4; ++mi) {
#pragma unroll
    for (int ni = 0; ni < 4; ++ni) {
#pragma unroll
      for (int r = 0; r < 4; ++r) {
        int row = m0 + ((wid >> 1) << 6) + mi * 16 + fg * 4 + r;
        int col = n0 + ((wid & 1) << 6) + ni * 16 + fr;
        float v = acc[mi][ni][r];
        if (EPI == 0) {
          ((float*)Cp)[(size_t)row * ldc + col] = v;
        } else {  // EPI == 3: fused SwiGLU
          float o = __shfl_xor(v, 1, 64);  // partner col (h1<->h3)
          if (!(fr & 1)) {
            float s = v / (1.0f + __expf(-v)) * o;
            ((u16*)Cp)[(size_t)row * ldc + (col >> 1)] = f2b(s);
          }
        }
      }
    }
  }
}

// ---------------- flash attention: 1 wave = 16 q-rows, KV tiles of 32 -----------
__global__ __launch_bounds__(256) void k_attn(const u16* __restrict__ qh,
                                              const u16* __restrict__ kh,
                                              const u16* __restrict__ vth,
                                              u16* __restrict__ attno, int isGlobal) {
  __shared__ u16 pb[4][512];  // per-wave P tile [16][32]
  const int qblk = blockIdx.x, hq = blockIdx.y, b = blockIdx.z;
  const int lane = threadIdx.x & 63, wid = threadIdx.x >> 6;
  const int fr = lane & 15, fg = lane >> 4;
  const int q0 = (qblk << 6) + (wid << 4);
  const int hk = hq >> 2;  // GQA: 4 q-heads per kv-head
  const u16* Q = qh + ((size_t)(b * HQ_ + hq) * S_) * HD_;
  const u16* Kh = kh + ((size_t)(b * HKV_ + hk) * S_) * HD_;
  const u16* VT = vth + ((size_t)(b * HKV_ + hk) * HD_) * S_;
  u16* pbuf = pb[wid];

  const s16x8 aq0 = *(const s16x8*)(Q + (q0 + fr) * HD_ + fg * 8);
  const s16x8 aq1 = *(const s16x8*)(Q + (q0 + fr) * HD_ + 32 + fg * 8);

  f32x4 o0 = {}, o1 = {}, o2 = {}, o3 = {};
  float m[4], l[4];
#pragma unroll
  for (int r = 0; r < 4; ++r) { m[r] = -1e30f; l[r] = 0.0f; }

  int kt0 = 0;
  if (!isGlobal) { int lo = q0 - (WINDOW_ - 1); if (lo > 0) kt0 = lo & ~31; }
  const int ktend = q0 + 16;

  for (int kt = kt0; kt < ktend; kt += 32) {
    // QK^T: scores [16 q][32 k] in two 16x16 accumulators
    f32x4 sc0 = {}, sc1 = {};
    {
      s16x8 b0 = *(const s16x8*)(Kh + (kt + fr) * HD_ + fg * 8);
      s16x8 b1 = *(const s16x8*)(Kh + (kt + fr) * HD_ + 32 + fg * 8);
      sc0 = __builtin_amdgcn_mfma_f32_16x16x32_bf16(aq0, b0, sc0, 0, 0, 0);
      sc0 = __builtin_amdgcn_mfma_f32_16x16x32_bf16(aq1, b1, sc0, 0, 0, 0);
      s16x8 c0 = *(const s16x8*)(Kh + (kt + 16 + fr) * HD_ + fg * 8);
      s16x8 c1 = *(const s16x8*)(Kh + (kt + 16 + fr) * HD_ + 32 + fg * 8);
      sc1 = __builtin_amdgcn_mfma_f32_16x16x32_bf16(aq0, c0, sc1, 0, 0, 0);
      sc1 = __builtin_amdgcn_mfma_f32_16x16x32_bf16(aq1, c1, sc1, 0, 0, 0);
    }
#pragma unroll
    for (int r = 0; r < 4; ++r) {
      int row = q0 + fg * 4 + r;
      int col0 = kt + fr, col1 = kt + 16 + fr;
      bool v0 = (col0 <= row) && (isGlobal || (row - col0) < WINDOW_);
      bool v1 = (col1 <= row) && (isGlobal || (row - col1) < WINDOW_);
      float s0 = v0 ? sc0[r] * 0.125f : -1e30f;
      float s1 = v1 ? sc1[r] * 0.125f : -1e30f;
      float t = fmaxf(s0, s1);
#pragma unroll
      for (int msk = 1; msk < 16; msk <<= 1) t = fmaxf(t, __shfl_xor(t, msk, 16));
      float mn = fmaxf(m[r], t);
      float fsc = __expf(m[r] - mn);  // -1e30 sentinel keeps this finite (exp(0)=1)
      m[r] = mn;
      float p0 = v0 ? __expf(s0 - mn) : 0.0f;  // mask by select, never by exp(-inf)
      float p1 = v1 ? __expf(s1 - mn) : 0.0f;
      float ps = p0 + p1;
#pragma unroll
      for (int msk = 1; msk < 16; msk <<= 1) ps += __shfl_xor(ps, msk, 16);
      l[r] = l[r] * fsc + ps;
      o0[r] *= fsc; o1[r] *= fsc; o2[r] *= fsc; o3[r] *= fsc;
      pbuf[(fg * 4 + r) * 32 + fr] = f2b(p0);
      pbuf[(fg * 4 + r) * 32 + 16 + fr] = f2b(p1);
    }
    // PV: P (from per-wave LDS, A-fragment layout) x V^T rows
    s16x8 ap = *(const s16x8*)(pbuf + fr * 32 + fg * 8);
    {
      s16x8 bv0 = *(const s16x8*)(VT + (size_t)(0 + fr) * S_ + kt + fg * 8);
      o0 = __builtin_amdgcn_mfma_f32_16x16x32_bf16(ap, bv0, o0, 0, 0, 0);
      s16x8 bv1 = *(const s16x8*)(VT + (size_t)(16 + fr) * S_ + kt + fg * 8);
      o1 = __builtin_amdgcn_mfma_f32_16x16x32_bf16(ap, bv1, o1, 0, 0, 0);
      s16x8 bv2 = *(const s16x8*)(VT + (size_t)(32 + fr) * S_ + kt + fg * 8);
      o2 = __builtin_amdgcn_mfma_f32_16x16x32_bf16(ap, bv2, o2, 0, 0, 0);
      s16x8 bv3 = *(const s16x8*)(VT + (size_t)(48 + fr) * S_ + kt + fg * 8);
      o3 = __builtin_amdgcn_mfma_f32_16x16x32_bf16(ap, bv3, o3, 0, 0, 0);
    }
  }

#pragma unroll
  for (int r = 0; r < 4; ++r) {
    int row = q0 + fg * 4 + r;
    float inv = 1.0f / l[r];
    size_t base = ((size_t)b * S_ + row) * (HQ_ * HD_) + hq * HD_;
    attno[base + fr] = f2b(o0[r] * inv);
    attno[base + 16 + fr] = f2b(o1[r] * inv);
    attno[base + 32 + fr] = f2b(o2[r] * inv);
    attno[base + 48 + fr] = f2b(o3[r] * inv);
  }
}

extern "C" void kernel_launch(void* const* d_in, const int* in_sizes, int n_in,
                              void* d_out, int out_size, void* d_ws, size_t ws_size,
                              hipStream_t stream) {
  (void)in_sizes; (void)n_in; (void)out_size; (void)ws_size;
  const int* idx = (const int*)d_in[0];
  const float* emb = (const float*)d_in[1];
  const float* Wq = (const float*)d_in[2];
  const float* Wk = (const float*)d_in[3];
  const float* Wv = (const float*)d_in[4];
  const float* Wo = (const float*)d_in[5];
  const float* w1 = (const float*)d_in[6];
  const float* w3 = (const float*)d_in[7];
  const float* w2 = (const float*)d_in[8];
  const float* n1 = (const float*)d_in[9];
  const float* n2 = (const float*)d_in[10];
  const float* nf = (const float*)d_in[11];
  float* out = (float*)d_out;

  char* p = (char*)d_ws;
  auto carve = [&](size_t bytes) {
    char* q = p;
    p += (bytes + 255) & ~(size_t)255;
    return (void*)q;
  };
  float* x = (float*)carve((size_t)BS_ * D_ * 4);
  u16* h = (u16*)carve((size_t)BS_ * D_ * 2);
  float* qkvf = (float*)carve((size_t)BS_ * 1536 * 4);
  u16* qh = (u16*)carve((size_t)B_ * HQ_ * S_ * HD_ * 2);
  u16* khb = (u16*)carve((size_t)B_ * HKV_ * S_ * HD_ * 2);
  u16* vth = (u16*)carve((size_t)B_ * HKV_ * HD_ * S_ * 2);
  u16* attno = (u16*)carve((size_t)BS_ * D_ * 2);
  u16* g = (u16*)carve((size_t)BS_ * H_ * 2);
  u16* wT = (u16*)carve((size_t)PACK_ * 2 * 2);  // double-buffered weight pack
  float* cosT = (float*)carve((size_t)S_ * 32 * 4);
  float* sinT = (float*)carve((size_t)S_ * 32 * 4);
  u16* embb = (u16*)carve((size_t)V_ * D_ * 2);

  auto makeT7 = [&](int l, u16* base) {
    T7 t7;
    t7.m[0] = { Wq + (size_t)l * D_ * 1024, base, D_, 1024, 0, 1, 0 };
    t7.m[1] = { Wk + (size_t)l * D_ * 256, base + 1048576, D_, 256, 1024, 1, 0 };
    t7.m[2] = { Wv + (size_t)l * D_ * 256, base + 1310720, D_, 256, 1280, 1, 0 };
    t7.m[3] = { Wo + (size_t)l * 1024 * D_, base + 1572864, 1024, D_, 1536, 1, 0 };
    // W1/W3 interleaved: w1 col j -> row 2j, w3 col j -> row 2j+1 (fused silu)
    t7.m[4] = { w1 + (size_t)l * D_ * H_, base + 2621440, D_, H_, 2560, 2, 0 };
    t7.m[5] = { w3 + (size_t)l * D_ * H_, base + 2621440, D_, H_, 5312, 2, 1 };
    t7.m[6] = { w2 + (size_t)l * H_ * D_, base + 8257536, H_, D_, 8064, 1, 0 };
    return t7;
  };

  // startup: emb->bf16, rope tables, embedding gather, layer-0 transpose
  k_init<<<34176 + 10816, 256, 0, stream>>>(emb, embb, cosT, sinT, idx, x,
                                            makeT7(0, wT));

  for (int l = 0; l < L_; ++l) {
    u16* wTl = wT + (size_t)(l & 1) * PACK_;

    k_rmsnorm<<<BS_, 256, 0, stream>>>(x, n1 + (size_t)l * D_, h);
    // QKV fused: BT = [WqT; WkT; WvT] (N=1536), fp32 out for RoPE precision
    k_gemm<0><<<dim3(16, 12), 256, 0, stream>>>(h, wTl, qkvf, 1024, 1024, 1536);
    k_ropev<<<BS_ + 256, 256, 0, stream>>>(qkvf, cosT, sinT, qh, khb, vth);
    int ig = ((l + 1) % 4) == 0;
    k_attn<<<dim3(16, HQ_, B_), 256, 0, stream>>>(qh, khb, vth, attno, ig);
    // x += attno @ Wo  (split-K=2, fp32 atomic accumulate into residual)
    k_gemm<4><<<dim3(16, 8, 2), 256, 0, stream>>>(attno, wTl + 1572864, x, 512, 1024, 1024);
    k_rmsnorm<<<BS_, 256, 0, stream>>>(x, n2 + (size_t)l * D_, h);
    // g = silu(h@W1) * (h@W3), fused: interleaved W13 pack, 256x128 tiles
    k_gemm2<3><<<dim3(8, 43), 512, 0, stream>>>(h, wTl + 2621440, g, 1024, 2752);
    // x += g @ W2 (split-K=2 atomic) + transpose next layer's pack on idle CUs
    const bool doTr = (l + 1) < L_;
    u16* wTn = wT + (size_t)((l + 1) & 1) * PACK_;
    k_gemmtr<<<doTr ? (256 + 10816) : 256, 256, 0, stream>>>(
        g, wTl + 8257536, x, 1376, 2752, 1024, makeT7(doTr ? l + 1 : 0, wTn));
  }

  k_rmsnorm<<<BS_, 256, 0, stream>>>(x, nf, h);
  // logits = xn @ emb^T  (BT = emb bf16), 256x128 tiles
  k_gemm2<0><<<dim3(8, 250), 512, 0, stream>>>(h, embb, out, 1024, 32000);
}

// Round 22
// 1470.089 us; speedup vs baseline: 1.0150x; 1.0150x over previous
//
#include <hip/hip_runtime.h>

#define V_ 32000
#define D_ 1024
#define L_ 8
#define HQ_ 16
#define HKV_ 4
#define HD_ 64
#define H_ 2752
#define B_ 2
#define S_ 1024
#define BS_ 2048
#define WINDOW_ 256

typedef float f32x4 __attribute__((ext_vector_type(4)));
typedef short s16x8 __attribute__((ext_vector_type(8)));
typedef unsigned short u16;

__device__ __forceinline__ u16 f2b(float f) {
  union { float f; unsigned u; } a; a.f = f;
  return (u16)((a.u + 0x7fffu + ((a.u >> 16) & 1u)) >> 16);
}
__device__ __forceinline__ float b2f(u16 b) {
  union { unsigned u; float f; } a; a.u = ((unsigned)b) << 16; return a.f;
}

// async global->LDS, 16B per lane. LDS dest must be wave-uniform; CK-style casts.
__device__ __forceinline__ void gload_lds16(const void* g, void* l) {
  __builtin_amdgcn_global_load_lds(
      (const __attribute__((address_space(1))) void*)(unsigned long long)(uintptr_t)g,
      (__attribute__((address_space(3))) void*)(unsigned int)(uintptr_t)l,
      16, 0, 0);
}

// ---------------- startup: emb cvt + rope table + embedding gather (1 launch) --
__global__ void k_init(const float* __restrict__ src, u16* __restrict__ dst,
                       float* __restrict__ cosT, float* __restrict__ sinT,
                       const int* __restrict__ idx, float* __restrict__ x) {
  int bid = blockIdx.x;
  if (bid < 32000) {  // cvt: 32000 blocks x 256 thr x float4 = V*D exactly
    long i = (long)bid * 256 + threadIdx.x;
    float4 v = ((const float4*)src)[i];
    ushort4 o; o.x = f2b(v.x); o.y = f2b(v.y); o.z = f2b(v.z); o.w = f2b(v.w);
    ((ushort4*)dst)[i] = o;
  } else if (bid < 32128) {  // ropetab: 128 blocks -> S*32 entries
    int i = (bid - 32000) * 256 + threadIdx.x;
    int s = i >> 5, d = i & 31;
    float inv = __expf(-((float)(2 * d) / (float)HD_) * logf(10000.0f));
    float f = (float)s * inv;
    cosT[i] = cosf(f); sinT[i] = sinf(f);
  } else {  // embed: 2048 blocks
    int t = bid - 32128;
    int token = idx[t];
    const float4* s = (const float4*)(src + (size_t)token * D_);
    float4* d = (float4*)(x + (size_t)t * D_);
    d[threadIdx.x] = s[threadIdx.x];
  }
}

// ---- fused per-layer prep: weight transpose-convert pack + rmsnorm1 (1 launch)
// blocks [0,10816): 7-matrix transpose into bf16 B^T pack (dst row = col*mul+add;
// W1/W3 interleave for the fused-silu epilogue). blocks [10816,10816+2048):
// rmsnorm of x into h. Disjoint outputs (wT vs h); both inputs ready at launch.
// Per-layer launch keeps the pack L2/L3-warm for the GEMMs (r17 lesson).
struct TMat { const float* src; u16* dst; int R, C, t0, mul, add; };
struct T7 { TMat m[7]; };

__global__ void k_tr_rms(T7 P, const float* __restrict__ x,
                         const float* __restrict__ w, u16* __restrict__ out) {
  __shared__ float tile[32][33];
  int bid = blockIdx.x;
  int tid = threadIdx.x;
  if (bid < 10816) {  // transpose path
    int mi = 0;
#pragma unroll
    for (int i = 1; i < 7; ++i) if (bid >= P.m[i].t0) mi = i;
    TMat mm = P.m[mi];
    int tl = bid - mm.t0;
    int ct = mm.C >> 5;
    int tr = tl / ct, tc = tl - tr * ct;
    int r0 = tr << 5, c0 = tc << 5;
    int tx = tid & 31, ty = tid >> 5;
#pragma unroll
    for (int j = 0; j < 4; ++j)
      tile[ty + j * 8][tx] = mm.src[(size_t)(r0 + ty + j * 8) * mm.C + c0 + tx];
    __syncthreads();
#pragma unroll
    for (int j = 0; j < 4; ++j)
      mm.dst[((size_t)(c0 + ty + j * 8) * mm.mul + mm.add) * mm.R + r0 + tx] =
          f2b(tile[tx][ty + j * 8]);
  } else {  // rmsnorm path
    int row = bid - 10816;
    float4 v = ((const float4*)(x + (size_t)row * D_))[tid];
    float ss = v.x * v.x + v.y * v.y + v.z * v.z + v.w * v.w;
#pragma unroll
    for (int m = 1; m < 64; m <<= 1) ss += __shfl_xor(ss, m, 64);
    if ((tid & 63) == 0) tile[0][tid >> 6] = ss;
    __syncthreads();
    float tot = tile[0][0] + tile[0][1] + tile[0][2] + tile[0][3];
    float rs = rsqrtf(tot * (1.0f / D_) + 1e-6f);
    float4 wv = ((const float4*)w)[tid];
    ushort4 o;
    o.x = f2b(v.x * rs * wv.x); o.y = f2b(v.y * rs * wv.y);
    o.z = f2b(v.z * rs * wv.z); o.w = f2b(v.w * rs * wv.w);
    ((ushort4*)(out + (size_t)row * D_))[tid] = o;
  }
}

// ---------------- rmsnorm (fp32 in) -> bf16 out ----------------
__global__ void k_rmsnorm(const float* __restrict__ x, const float* __restrict__ w,
                          u16* __restrict__ out) {
  int row = blockIdx.x, tid = threadIdx.x;
  float4 v = ((const float4*)(x + (size_t)row * D_))[tid];
  float ss = v.x * v.x + v.y * v.y + v.z * v.z + v.w * v.w;
#pragma unroll
  for (int m = 1; m < 64; m <<= 1) ss += __shfl_xor(ss, m, 64);
  __shared__ float red[4];
  if ((tid & 63) == 0) red[tid >> 6] = ss;
  __syncthreads();
  float tot = red[0] + red[1] + red[2] + red[3];
  float rs = rsqrtf(tot * (1.0f / D_) + 1e-6f);
  float4 wv = ((const float4*)w)[tid];
  ushort4 o;
  o.x = f2b(v.x * rs * wv.x); o.y = f2b(v.y * rs * wv.y);
  o.z = f2b(v.z * rs * wv.z); o.w = f2b(v.w * rs * wv.w);
  ((ushort4*)(out + (size_t)row * D_))[tid] = o;
}

// ---------------- fused rope (q,k) + V transpose; one launch/layer ------------
__global__ void k_ropev(const float* __restrict__ qkvf, const float* __restrict__ cosT,
                        const float* __restrict__ sinT, u16* __restrict__ qh,
                        u16* __restrict__ kh, u16* __restrict__ vth) {
  __shared__ float tile[32][65];
  int bid = blockIdx.x;
  int tid = threadIdx.x;
  if (bid < BS_) {  // RoPE: q + k head-major
    int t = bid;
    int b = t >> 10, s = t & (S_ - 1);
    const float* row = qkvf + (size_t)t * 1536;
    for (int p = tid; p < 512; p += 256) {           // q: 512 pairs
      int hh = p >> 5, d = p & 31;
      float x0 = row[hh * 64 + 2 * d], x1 = row[hh * 64 + 2 * d + 1];
      float c = cosT[s * 32 + d], sn = sinT[s * 32 + d];
      size_t o = ((size_t)(b * HQ_ + hh) * S_ + s) * HD_ + 2 * d;
      qh[o] = f2b(x0 * c - x1 * sn);
      qh[o + 1] = f2b(x0 * sn + x1 * c);
    }
    if (tid < 128) {                                  // k: 128 pairs
      int hh = tid >> 5, d = tid & 31;
      float x0 = row[1024 + hh * 64 + 2 * d], x1 = row[1024 + hh * 64 + 2 * d + 1];
      float c = cosT[s * 32 + d], sn = sinT[s * 32 + d];
      size_t o = ((size_t)(b * HKV_ + hh) * S_ + s) * HD_ + 2 * d;
      kh[o] = f2b(x0 * c - x1 * sn);
      kh[o + 1] = f2b(x0 * sn + x1 * c);
    }
  } else {  // V transpose -> vth [b][kvh][64][S]
    int v = bid - BS_;                // 0..255
    const int s0 = (v & 31) << 5, hh = (v >> 5) & 3, b = v >> 7;
    const int tx = tid & 63, ty = tid >> 6;  // load: 64 d x 4 s-rows
#pragma unroll
    for (int j = 0; j < 8; ++j) {
      int sl = j * 4 + ty;
      tile[sl][tx] = qkvf[(size_t)((b << 10) + s0 + sl) * 1536 + 1280 + hh * 64 + tx];
    }
    __syncthreads();
    const int sx = tid & 31, dr = tid >> 5;  // store: 32 s x 8 d-rows
#pragma unroll
    for (int j = 0; j < 8; ++j) {
      int d = j * 8 + dr;
      vth[((size_t)((b * HKV_ + hh) << 6) + d) * S_ + s0 + sx] = f2b(tile[sx][d]);
    }
  }
}

// ---------------- 128x128 bf16 MFMA GEMM: C = A[M,*] @ BT[N,*]^T ----------------
// Depth-2 prefetch, 3-buffer rotation, counted vmcnt (r9/r10/r12 verified best).
// kdepth = K handled by this block (split-K via blockIdx.z); lda = row stride.
// EPI: 0 = f32 store, 4 = fp32 atomicAdd (split-K residual accumulate)
template <int EPI>
__global__ __launch_bounds__(256) void k_gemm(const u16* __restrict__ A,
                                              const u16* __restrict__ BT,
                                              void* __restrict__ Cp, int kdepth,
                                              int lda, int ldc) {
  __shared__ u16 As[3][4096];  // [8 blocks16][64 slots][8 u16] x 3 buffers
  __shared__ u16 Bs[3][4096];
  const int tid = threadIdx.x;
  const int lane = tid & 63, wid = tid >> 6;
  const int lin = blockIdx.y * 16 + blockIdx.x;
  const int cpx = (gridDim.x * gridDim.y) >> 3;
  const int swz = (lin & 7) * cpx + (lin >> 3);
  const int m0 = (swz & 15) << 7, n0 = (swz >> 4) << 7;
  const int wm = (wid >> 1) << 6, wn = (wid & 1) << 6;
  const int fr = lane & 15, fg = lane >> 4;

  f32x4 acc[4][4] = {};

  const int srow = (wid << 4) + (lane >> 2);
  const int scol = ((lane & 3) - ((lane >> 3) & 3)) & 3;
  const int kz = blockIdx.z * kdepth;
  const u16* ga = A + (size_t)(m0 + srow) * lda + kz + (scol << 3);
  const u16* gb = BT + (size_t)(n0 + srow) * lda + kz + (scol << 3);
  const int cb = wid << 9;  // wave-uniform LDS chunk base (u16 units)

  auto stage = [&](int buf, int k0) {
    u16* la = &As[buf][cb];
    u16* lb = &Bs[buf][cb];
    gload_lds16(ga + k0, la);
    gload_lds16(ga + (size_t)64 * lda + k0, la + 2048);
    gload_lds16(gb + k0, lb);
    gload_lds16(gb + (size_t)64 * lda + k0, lb + 2048);
  };

  const int nk = kdepth >> 5;
  stage(0, 0);
  stage(1, 32);

  const int ab = (wid >> 1) << 2, bb = (wid & 1) << 2;  // 16-row block bases
  const int foff = (fr << 5) + ((((fg + (fr >> 1)) & 3)) << 3);
  int cur = 0;
  for (int t = 0; t < nk; ++t) {
    if (t + 2 < nk) {
      int nb = cur + 2; if (nb >= 3) nb -= 3;
      stage(nb, (t + 2) << 5);
      asm volatile("s_waitcnt vmcnt(8)" ::: "memory");   // tile t retired; t+1,t+2 in flight
    } else if (t + 2 == nk) {
      asm volatile("s_waitcnt vmcnt(4)" ::: "memory");
    } else {
      asm volatile("s_waitcnt vmcnt(0)" ::: "memory");
    }
    __builtin_amdgcn_s_barrier();  // all waves' tile-t writes visible
    s16x8 af[4], bq[4];
#pragma unroll
    for (int i = 0; i < 4; ++i) {
      af[i] = *(const s16x8*)(&As[cur][((ab + i) << 9) + foff]);
      bq[i] = *(const s16x8*)(&Bs[cur][((bb + i) << 9) + foff]);
    }
#pragma unroll
    for (int mi = 0; mi < 4; ++mi)
#pragma unroll
      for (int ni = 0; ni < 4; ++ni)
        acc[mi][ni] = __builtin_amdgcn_mfma_f32_16x16x32_bf16(af[mi], bq[ni], acc[mi][ni], 0, 0, 0);
    __builtin_amdgcn_s_barrier();  // reads of buf(t) done before t+3 overwrites
    if (++cur == 3) cur = 0;
  }

#pragma unroll
  for (int mi = 0; mi < 4; ++mi) {
#pragma unroll
    for (int ni = 0; ni < 4; ++ni) {
#pragma unroll
      for (int r = 0; r < 4; ++r) {
        int row = m0 + wm + mi * 16 + fg * 4 + r;
        int col = n0 + wn + ni * 16 + fr;
        size_t off = (size_t)row * ldc + col;
        float v = acc[mi][ni][r];
        if (EPI == 0) ((float*)Cp)[off] = v;
        else atomicAdd((float*)Cp + off, v);
      }
    }
  }
}

// ---------------- 256x128 bf16 MFMA GEMM (big-N: lm_head, h13) ----------------
// 512 threads / 8 waves (4M x 2N, 64x64 out each): 16 waves/CU = 4 waves/SIMD.
// Depth-2 3-buffer counted-vmcnt schedule (r12 verified best); 3 loads/wave/stage.
// EPI: 0 = f32 store, 3 = fused SwiGLU (interleaved W13 pack; even lanes write
// silu(h1)*h3 bf16 to g, ldc = 2752).
template <int EPI>
__global__ __launch_bounds__(512, 4) void k_gemm2(const u16* __restrict__ A,
                                                  const u16* __restrict__ BT,
                                                  void* __restrict__ Cp, int K, int ldc) {
  __shared__ u16 As[3][8192];  // [16 blocks16][512 u16] x 3
  __shared__ u16 Bs[3][4096];  // [8 blocks16]
  const int tid = threadIdx.x;
  const int lane = tid & 63, wid = tid >> 6;  // 8 waves
  const int lin = blockIdx.y * gridDim.x + blockIdx.x;  // gridDim.x == 8
  const int cpx = (gridDim.x * gridDim.y) >> 3;
  const int swz = (lin & 7) * cpx + (lin >> 3);
  const int m0 = (swz & 7) << 8, n0 = (swz >> 3) << 7;
  const int fr = lane & 15, fg = lane >> 4;

  f32x4 acc[4][4] = {};

  const int srow = lane >> 2;  // 0..15 within a 16-row block
  const int scol = ((lane & 3) - ((lane >> 3) & 3)) & 3;
  // wave w stages A rows [32w,32w+32) -> blocks 2w,2w+1 ; B rows [16w,16w+16) -> block w
  const u16* ga = A + (size_t)(m0 + (wid << 5) + srow) * K + (scol << 3);
  const u16* gb = BT + (size_t)(n0 + (wid << 4) + srow) * K + (scol << 3);
  const int cba = wid << 10;  // 2 blocks * 512 u16
  const int cbb = wid << 9;   // 1 block * 512 u16

  auto stage = [&](int buf, int k0) {
    gload_lds16(ga + k0, &As[buf][cba]);
    gload_lds16(ga + (size_t)16 * K + k0, &As[buf][cba + 512]);
    gload_lds16(gb + k0, &Bs[buf][cbb]);
  };

  const int nk = K >> 5;
  stage(0, 0);
  stage(1, 32);

  const int am = (wid >> 1) << 2;  // A block base: wave M-group * 4
  const int bn = (wid & 1) << 2;   // B block base: wave N-group * 4
  const int foff = (fr << 5) + ((((fg + (fr >> 1)) & 3)) << 3);
  int cur = 0;
  for (int t = 0; t < nk; ++t) {
    if (t + 2 < nk) {
      int nb = cur + 2; if (nb >= 3) nb -= 3;
      stage(nb, (t + 2) << 5);
      asm volatile("s_waitcnt vmcnt(6)" ::: "memory");  // tile t retired; t+1,t+2 in flight
    } else if (t + 2 == nk) {
      asm volatile("s_waitcnt vmcnt(3)" ::: "memory");
    } else {
      asm volatile("s_waitcnt vmcnt(0)" ::: "memory");
    }
    __builtin_amdgcn_s_barrier();
    s16x8 af[4], bq[4];
#pragma unroll
    for (int i = 0; i < 4; ++i) {
      af[i] = *(const s16x8*)(&As[cur][((am + i) << 9) + foff]);
      bq[i] = *(const s16x8*)(&Bs[cur][((bn + i) << 9) + foff]);
    }
#pragma unroll
    for (int mi = 0; mi < 4; ++mi)
#pragma unroll
      for (int ni = 0; ni < 4; ++ni)
        acc[mi][ni] = __builtin_amdgcn_mfma_f32_16x16x32_bf16(af[mi], bq[ni], acc[mi][ni], 0, 0, 0);
    __builtin_amdgcn_s_barrier();
    if (++cur == 3) cur = 0;
  }

#pragma unroll
  for (int mi = 0; mi < 4; ++mi) {
#pragma unroll
    for (int ni = 0; ni < 4; ++ni) {
#pragma unroll
      for (int r = 0; r < 4; ++r) {
        int row = m0 + ((wid >> 1) << 6) + mi * 16 + fg * 4 + r;
        int col = n0 + ((wid & 1) << 6) + ni * 16 + fr;
        float v = acc[mi][ni][r];
        if (EPI == 0) {
          ((float*)Cp)[(size_t)row * ldc + col] = v;
        } else {  // EPI == 3: fused SwiGLU
          float o = __shfl_xor(v, 1, 64);  // partner col (h1<->h3)
          if (!(fr & 1)) {
            float s = v / (1.0f + __expf(-v)) * o;
            ((u16*)Cp)[(size_t)row * ldc + (col >> 1)] = f2b(s);
          }
        }
      }
    }
  }
}

// ---------------- flash attention: 1 wave = 16 q-rows, KV tiles of 32 -----------
__global__ __launch_bounds__(256) void k_attn(const u16* __restrict__ qh,
                                              const u16* __restrict__ kh,
                                              const u16* __restrict__ vth,
                                              u16* __restrict__ attno, int isGlobal) {
  __shared__ u16 pb[4][512];  // per-wave P tile [16][32]
  const int qblk = blockIdx.x, hq = blockIdx.y, b = blockIdx.z;
  const int lane = threadIdx.x & 63, wid = threadIdx.x >> 6;
  const int fr = lane & 15, fg = lane >> 4;
  const int q0 = (qblk << 6) + (wid << 4);
  const int hk = hq >> 2;  // GQA: 4 q-heads per kv-head
  const u16* Q = qh + ((size_t)(b * HQ_ + hq) * S_) * HD_;
  const u16* Kh = kh + ((size_t)(b * HKV_ + hk) * S_) * HD_;
  const u16* VT = vth + ((size_t)(b * HKV_ + hk) * HD_) * S_;
  u16* pbuf = pb[wid];

  const s16x8 aq0 = *(const s16x8*)(Q + (q0 + fr) * HD_ + fg * 8);
  const s16x8 aq1 = *(const s16x8*)(Q + (q0 + fr) * HD_ + 32 + fg * 8);

  f32x4 o0 = {}, o1 = {}, o2 = {}, o3 = {};
  float m[4], l[4];
#pragma unroll
  for (int r = 0; r < 4; ++r) { m[r] = -1e30f; l[r] = 0.0f; }

  int kt0 = 0;
  if (!isGlobal) { int lo = q0 - (WINDOW_ - 1); if (lo > 0) kt0 = lo & ~31; }
  const int ktend = q0 + 16;

  for (int kt = kt0; kt < ktend; kt += 32) {
    // QK^T: scores [16 q][32 k] in two 16x16 accumulators
    f32x4 sc0 = {}, sc1 = {};
    {
      s16x8 b0 = *(const s16x8*)(Kh + (kt + fr) * HD_ + fg * 8);
      s16x8 b1 = *(const s16x8*)(Kh + (kt + fr) * HD_ + 32 + fg * 8);
      sc0 = __builtin_amdgcn_mfma_f32_16x16x32_bf16(aq0, b0, sc0, 0, 0, 0);
      sc0 = __builtin_amdgcn_mfma_f32_16x16x32_bf16(aq1, b1, sc0, 0, 0, 0);
      s16x8 c0 = *(const s16x8*)(Kh + (kt + 16 + fr) * HD_ + fg * 8);
      s16x8 c1 = *(const s16x8*)(Kh + (kt + 16 + fr) * HD_ + 32 + fg * 8);
      sc1 = __builtin_amdgcn_mfma_f32_16x16x32_bf16(aq0, c0, sc1, 0, 0, 0);
      sc1 = __builtin_amdgcn_mfma_f32_16x16x32_bf16(aq1, c1, sc1, 0, 0, 0);
    }
#pragma unroll
    for (int r = 0; r < 4; ++r) {
      int row = q0 + fg * 4 + r;
      int col0 = kt + fr, col1 = kt + 16 + fr;
      bool v0 = (col0 <= row) && (isGlobal || (row - col0) < WINDOW_);
      bool v1 = (col1 <= row) && (isGlobal || (row - col1) < WINDOW_);
      float s0 = v0 ? sc0[r] * 0.125f : -1e30f;
      float s1 = v1 ? sc1[r] * 0.125f : -1e30f;
      float t = fmaxf(s0, s1);
#pragma unroll
      for (int msk = 1; msk < 16; msk <<= 1) t = fmaxf(t, __shfl_xor(t, msk, 16));
      float mn = fmaxf(m[r], t);
      float fsc = __expf(m[r] - mn);  // -1e30 sentinel keeps this finite (exp(0)=1)
      m[r] = mn;
      float p0 = v0 ? __expf(s0 - mn) : 0.0f;  // mask by select, never by exp(-inf)
      float p1 = v1 ? __expf(s1 - mn) : 0.0f;
      float ps = p0 + p1;
#pragma unroll
      for (int msk = 1; msk < 16; msk <<= 1) ps += __shfl_xor(ps, msk, 16);
      l[r] = l[r] * fsc + ps;
      o0[r] *= fsc; o1[r] *= fsc; o2[r] *= fsc; o3[r] *= fsc;
      pbuf[(fg * 4 + r) * 32 + fr] = f2b(p0);
      pbuf[(fg * 4 + r) * 32 + 16 + fr] = f2b(p1);
    }
    // PV: P (from per-wave LDS, A-fragment layout) x V^T rows
    s16x8 ap = *(const s16x8*)(pbuf + fr * 32 + fg * 8);
    {
      s16x8 bv0 = *(const s16x8*)(VT + (size_t)(0 + fr) * S_ + kt + fg * 8);
      o0 = __builtin_amdgcn_mfma_f32_16x16x32_bf16(ap, bv0, o0, 0, 0, 0);
      s16x8 bv1 = *(const s16x8*)(VT + (size_t)(16 + fr) * S_ + kt + fg * 8);
      o1 = __builtin_amdgcn_mfma_f32_16x16x32_bf16(ap, bv1, o1, 0, 0, 0);
      s16x8 bv2 = *(const s16x8*)(VT + (size_t)(32 + fr) * S_ + kt + fg * 8);
      o2 = __builtin_amdgcn_mfma_f32_16x16x32_bf16(ap, bv2, o2, 0, 0, 0);
      s16x8 bv3 = *(const s16x8*)(VT + (size_t)(48 + fr) * S_ + kt + fg * 8);
      o3 = __builtin_amdgcn_mfma_f32_16x16x32_bf16(ap, bv3, o3, 0, 0, 0);
    }
  }

#pragma unroll
  for (int r = 0; r < 4; ++r) {
    int row = q0 + fg * 4 + r;
    float inv = 1.0f / l[r];
    size_t base = ((size_t)b * S_ + row) * (HQ_ * HD_) + hq * HD_;
    attno[base + fr] = f2b(o0[r] * inv);
    attno[base + 16 + fr] = f2b(o1[r] * inv);
    attno[base + 32 + fr] = f2b(o2[r] * inv);
    attno[base + 48 + fr] = f2b(o3[r] * inv);
  }
}

extern "C" void kernel_launch(void* const* d_in, const int* in_sizes, int n_in,
                              void* d_out, int out_size, void* d_ws, size_t ws_size,
                              hipStream_t stream) {
  (void)in_sizes; (void)n_in; (void)out_size; (void)ws_size;
  const int* idx = (const int*)d_in[0];
  const float* emb = (const float*)d_in[1];
  const float* Wq = (const float*)d_in[2];
  const float* Wk = (const float*)d_in[3];
  const float* Wv = (const float*)d_in[4];
  const float* Wo = (const float*)d_in[5];
  const float* w1 = (const float*)d_in[6];
  const float* w3 = (const float*)d_in[7];
  const float* w2 = (const float*)d_in[8];
  const float* n1 = (const float*)d_in[9];
  const float* n2 = (const float*)d_in[10];
  const float* nf = (const float*)d_in[11];
  float* out = (float*)d_out;

  char* p = (char*)d_ws;
  auto carve = [&](size_t bytes) {
    char* q = p;
    p += (bytes + 255) & ~(size_t)255;
    return (void*)q;
  };
  float* x = (float*)carve((size_t)BS_ * D_ * 4);
  u16* h = (u16*)carve((size_t)BS_ * D_ * 2);
  float* qkvf = (float*)carve((size_t)BS_ * 1536 * 4);
  u16* qh = (u16*)carve((size_t)B_ * HQ_ * S_ * HD_ * 2);
  u16* khb = (u16*)carve((size_t)B_ * HKV_ * S_ * HD_ * 2);
  u16* vth = (u16*)carve((size_t)B_ * HKV_ * HD_ * S_ * 2);
  u16* attno = (u16*)carve((size_t)BS_ * D_ * 2);
  u16* g = (u16*)carve((size_t)BS_ * H_ * 2);
  u16* wT = (u16*)carve((size_t)11075584 * 2);
  float* cosT = (float*)carve((size_t)S_ * 32 * 4);
  float* sinT = (float*)carve((size_t)S_ * 32 * 4);
  u16* embb = (u16*)carve((size_t)V_ * D_ * 2);

  // startup: emb->bf16, rope tables, token-embedding gather (single launch)
  k_init<<<32000 + 128 + BS_, 256, 0, stream>>>(emb, embb, cosT, sinT, idx, x);

  for (int l = 0; l < L_; ++l) {
    T7 t7;
    t7.m[0] = { Wq + (size_t)l * D_ * 1024, wT, D_, 1024, 0, 1, 0 };
    t7.m[1] = { Wk + (size_t)l * D_ * 256, wT + 1048576, D_, 256, 1024, 1, 0 };
    t7.m[2] = { Wv + (size_t)l * D_ * 256, wT + 1310720, D_, 256, 1280, 1, 0 };
    t7.m[3] = { Wo + (size_t)l * 1024 * D_, wT + 1572864, 1024, D_, 1536, 1, 0 };
    // W1/W3 interleaved: w1 col j -> row 2j, w3 col j -> row 2j+1 (fused silu)
    t7.m[4] = { w1 + (size_t)l * D_ * H_, wT + 2621440, D_, H_, 2560, 2, 0 };
    t7.m[5] = { w3 + (size_t)l * D_ * H_, wT + 2621440, D_, H_, 5312, 2, 1 };
    t7.m[6] = { w2 + (size_t)l * H_ * D_, wT + 8257536, H_, D_, 8064, 1, 0 };

    // fused: weight pack transpose + rmsnorm1 (one launch)
    k_tr_rms<<<10816 + BS_, 256, 0, stream>>>(t7, x, n1 + (size_t)l * D_, h);
    // QKV fused: BT = [WqT; WkT; WvT] (N=1536), fp32 out for RoPE precision
    k_gemm<0><<<dim3(16, 12), 256, 0, stream>>>(h, wT, qkvf, 1024, 1024, 1536);
    k_ropev<<<BS_ + 256, 256, 0, stream>>>(qkvf, cosT, sinT, qh, khb, vth);
    int ig = ((l + 1) % 4) == 0;
    k_attn<<<dim3(16, HQ_, B_), 256, 0, stream>>>(qh, khb, vth, attno, ig);
    // x += attno @ Wo  (split-K=2, fp32 atomic accumulate into residual)
    k_gemm<4><<<dim3(16, 8, 2), 256, 0, stream>>>(attno, wT + 1572864, x, 512, 1024, 1024);
    k_rmsnorm<<<BS_, 256, 0, stream>>>(x, n2 + (size_t)l * D_, h);
    // g = silu(h@W1) * (h@W3), fused: interleaved W13 pack, 256x128 tiles
    k_gemm2<3><<<dim3(8, 43), 512, 0, stream>>>(h, wT + 2621440, g, 1024, 2752);
    // x += g @ W2  (split-K=2 atomic)
    k_gemm<4><<<dim3(16, 8, 2), 256, 0, stream>>>(g, wT + 8257536, x, 1376, 2752, 1024);
  }

  k_rmsnorm<<<BS_, 256, 0, stream>>>(x, nf, h);
  // logits = xn @ emb^T  (BT = emb bf16), 256x128 tiles
  k_gemm2<0><<<dim3(8, 250), 512, 0, stream>>>(h, embb, out, 1024, 32000);
}

// Round 23
// 1456.166 us; speedup vs baseline: 1.0247x; 1.0096x over previous
//
#include <hip/hip_runtime.h>

#define V_ 32000
#define D_ 1024
#define L_ 8
#define HQ_ 16
#define HKV_ 4
#define HD_ 64
#define H_ 2752
#define B_ 2
#define S_ 1024
#define BS_ 2048
#define WINDOW_ 256

typedef float f32x4 __attribute__((ext_vector_type(4)));
typedef short s16x8 __attribute__((ext_vector_type(8)));
typedef unsigned short u16;

__device__ __forceinline__ u16 f2b(float f) {
  union { float f; unsigned u; } a; a.f = f;
  return (u16)((a.u + 0x7fffu + ((a.u >> 16) & 1u)) >> 16);
}
__device__ __forceinline__ float b2f(u16 b) {
  union { unsigned u; float f; } a; a.u = ((unsigned)b) << 16; return a.f;
}

// async global->LDS, 16B per lane. LDS dest must be wave-uniform; CK-style casts.
__device__ __forceinline__ void gload_lds16(const void* g, void* l) {
  __builtin_amdgcn_global_load_lds(
      (const __attribute__((address_space(1))) void*)(unsigned long long)(uintptr_t)g,
      (__attribute__((address_space(3))) void*)(unsigned int)(uintptr_t)l,
      16, 0, 0);
}

// ---------------- startup: emb cvt + rope table + embedding gather (1 launch) --
__global__ void k_init(const float* __restrict__ src, u16* __restrict__ dst,
                       float* __restrict__ cosT, float* __restrict__ sinT,
                       const int* __restrict__ idx, float* __restrict__ x) {
  int bid = blockIdx.x;
  if (bid < 32000) {  // cvt: 32000 blocks x 256 thr x float4 = V*D exactly
    long i = (long)bid * 256 + threadIdx.x;
    float4 v = ((const float4*)src)[i];
    ushort4 o; o.x = f2b(v.x); o.y = f2b(v.y); o.z = f2b(v.z); o.w = f2b(v.w);
    ((ushort4*)dst)[i] = o;
  } else if (bid < 32128) {  // ropetab: 128 blocks -> S*32 entries
    int i = (bid - 32000) * 256 + threadIdx.x;
    int s = i >> 5, d = i & 31;
    float inv = __expf(-((float)(2 * d) / (float)HD_) * logf(10000.0f));
    float f = (float)s * inv;
    cosT[i] = cosf(f); sinT[i] = sinf(f);
  } else {  // embed: 2048 blocks
    int t = bid - 32128;
    int token = idx[t];
    const float4* s = (const float4*)(src + (size_t)token * D_);
    float4* d = (float4*)(x + (size_t)t * D_);
    d[threadIdx.x] = s[threadIdx.x];
  }
}

// ---- fused per-layer prep: weight transpose-convert pack + rmsnorm1 (1 launch)
// blocks [0,10816): 7-matrix transpose into bf16 B^T pack (dst row = col*mul+add;
// W1/W3 interleave for the fused-silu epilogue). blocks [10816,10816+2048):
// rmsnorm of x into h. Disjoint outputs (wT vs h); both inputs ready at launch.
// Per-layer launch keeps the pack L2/L3-warm for the GEMMs (r17 lesson).
struct TMat { const float* src; u16* dst; int R, C, t0, mul, add; };
struct T7 { TMat m[7]; };

__global__ void k_tr_rms(T7 P, const float* __restrict__ x,
                         const float* __restrict__ w, u16* __restrict__ out) {
  __shared__ float tile[32][33];
  int bid = blockIdx.x;
  int tid = threadIdx.x;
  if (bid < 10816) {  // transpose path
    int mi = 0;
#pragma unroll
    for (int i = 1; i < 7; ++i) if (bid >= P.m[i].t0) mi = i;
    TMat mm = P.m[mi];
    int tl = bid - mm.t0;
    int ct = mm.C >> 5;
    int tr = tl / ct, tc = tl - tr * ct;
    int r0 = tr << 5, c0 = tc << 5;
    int tx = tid & 31, ty = tid >> 5;
#pragma unroll
    for (int j = 0; j < 4; ++j)
      tile[ty + j * 8][tx] = mm.src[(size_t)(r0 + ty + j * 8) * mm.C + c0 + tx];
    __syncthreads();
#pragma unroll
    for (int j = 0; j < 4; ++j)
      mm.dst[((size_t)(c0 + ty + j * 8) * mm.mul + mm.add) * mm.R + r0 + tx] =
          f2b(tile[tx][ty + j * 8]);
  } else {  // rmsnorm path
    int row = bid - 10816;
    float4 v = ((const float4*)(x + (size_t)row * D_))[tid];
    float ss = v.x * v.x + v.y * v.y + v.z * v.z + v.w * v.w;
#pragma unroll
    for (int m = 1; m < 64; m <<= 1) ss += __shfl_xor(ss, m, 64);
    if ((tid & 63) == 0) tile[0][tid >> 6] = ss;
    __syncthreads();
    float tot = tile[0][0] + tile[0][1] + tile[0][2] + tile[0][3];
    float rs = rsqrtf(tot * (1.0f / D_) + 1e-6f);
    float4 wv = ((const float4*)w)[tid];
    ushort4 o;
    o.x = f2b(v.x * rs * wv.x); o.y = f2b(v.y * rs * wv.y);
    o.z = f2b(v.z * rs * wv.z); o.w = f2b(v.w * rs * wv.w);
    ((ushort4*)(out + (size_t)row * D_))[tid] = o;
  }
}

// ---------------- rmsnorm (fp32 in) -> bf16 out ----------------
__global__ void k_rmsnorm(const float* __restrict__ x, const float* __restrict__ w,
                          u16* __restrict__ out) {
  int row = blockIdx.x, tid = threadIdx.x;
  float4 v = ((const float4*)(x + (size_t)row * D_))[tid];
  float ss = v.x * v.x + v.y * v.y + v.z * v.z + v.w * v.w;
#pragma unroll
  for (int m = 1; m < 64; m <<= 1) ss += __shfl_xor(ss, m, 64);
  __shared__ float red[4];
  if ((tid & 63) == 0) red[tid >> 6] = ss;
  __syncthreads();
  float tot = red[0] + red[1] + red[2] + red[3];
  float rs = rsqrtf(tot * (1.0f / D_) + 1e-6f);
  float4 wv = ((const float4*)w)[tid];
  ushort4 o;
  o.x = f2b(v.x * rs * wv.x); o.y = f2b(v.y * rs * wv.y);
  o.z = f2b(v.z * rs * wv.z); o.w = f2b(v.w * rs * wv.w);
  ((ushort4*)(out + (size_t)row * D_))[tid] = o;
}

// ---------------- fused rope (q,k) + V transpose; one launch/layer ------------
// qkvb is the bf16 qkv GEMM output (r23: halves the fp32 round-trip traffic;
// RoPE on bf16-rounded q/k adds one quantization, ~0.2% rel, V path exact).
__global__ void k_ropev(const u16* __restrict__ qkvb, const float* __restrict__ cosT,
                        const float* __restrict__ sinT, u16* __restrict__ qh,
                        u16* __restrict__ kh, u16* __restrict__ vth) {
  __shared__ float tile[32][65];
  int bid = blockIdx.x;
  int tid = threadIdx.x;
  if (bid < BS_) {  // RoPE: q + k head-major
    int t = bid;
    int b = t >> 10, s = t & (S_ - 1);
    const u16* row = qkvb + (size_t)t * 1536;
    for (int p = tid; p < 512; p += 256) {           // q: 512 pairs
      int hh = p >> 5, d = p & 31;
      float x0 = b2f(row[hh * 64 + 2 * d]), x1 = b2f(row[hh * 64 + 2 * d + 1]);
      float c = cosT[s * 32 + d], sn = sinT[s * 32 + d];
      size_t o = ((size_t)(b * HQ_ + hh) * S_ + s) * HD_ + 2 * d;
      qh[o] = f2b(x0 * c - x1 * sn);
      qh[o + 1] = f2b(x0 * sn + x1 * c);
    }
    if (tid < 128) {                                  // k: 128 pairs
      int hh = tid >> 5, d = tid & 31;
      float x0 = b2f(row[1024 + hh * 64 + 2 * d]), x1 = b2f(row[1024 + hh * 64 + 2 * d + 1]);
      float c = cosT[s * 32 + d], sn = sinT[s * 32 + d];
      size_t o = ((size_t)(b * HKV_ + hh) * S_ + s) * HD_ + 2 * d;
      kh[o] = f2b(x0 * c - x1 * sn);
      kh[o + 1] = f2b(x0 * sn + x1 * c);
    }
  } else {  // V transpose -> vth [b][kvh][64][S] (bf16->f32->bf16 is exact)
    int v = bid - BS_;                // 0..255
    const int s0 = (v & 31) << 5, hh = (v >> 5) & 3, b = v >> 7;
    const int tx = tid & 63, ty = tid >> 6;  // load: 64 d x 4 s-rows
#pragma unroll
    for (int j = 0; j < 8; ++j) {
      int sl = j * 4 + ty;
      tile[sl][tx] = b2f(qkvb[(size_t)((b << 10) + s0 + sl) * 1536 + 1280 + hh * 64 + tx]);
    }
    __syncthreads();
    const int sx = tid & 31, dr = tid >> 5;  // store: 32 s x 8 d-rows
#pragma unroll
    for (int j = 0; j < 8; ++j) {
      int d = j * 8 + dr;
      vth[((size_t)((b * HKV_ + hh) << 6) + d) * S_ + s0 + sx] = f2b(tile[sx][d]);
    }
  }
}

// ---------------- 128x128 bf16 MFMA GEMM: C = A[M,*] @ BT[N,*]^T ----------------
// Depth-2 prefetch, 3-buffer rotation, counted vmcnt (r9/r10/r12 verified best).
// kdepth = K handled by this block (split-K via blockIdx.z); lda = row stride.
// EPI: 0 = f32 store, 2 = bf16 store, 4 = fp32 atomicAdd (split-K accumulate)
template <int EPI>
__global__ __launch_bounds__(256) void k_gemm(const u16* __restrict__ A,
                                              const u16* __restrict__ BT,
                                              void* __restrict__ Cp, int kdepth,
                                              int lda, int ldc) {
  __shared__ u16 As[3][4096];  // [8 blocks16][64 slots][8 u16] x 3 buffers
  __shared__ u16 Bs[3][4096];
  const int tid = threadIdx.x;
  const int lane = tid & 63, wid = tid >> 6;
  const int lin = blockIdx.y * 16 + blockIdx.x;
  const int cpx = (gridDim.x * gridDim.y) >> 3;
  const int swz = (lin & 7) * cpx + (lin >> 3);
  const int m0 = (swz & 15) << 7, n0 = (swz >> 4) << 7;
  const int wm = (wid >> 1) << 6, wn = (wid & 1) << 6;
  const int fr = lane & 15, fg = lane >> 4;

  f32x4 acc[4][4] = {};

  const int srow = (wid << 4) + (lane >> 2);
  const int scol = ((lane & 3) - ((lane >> 3) & 3)) & 3;
  const int kz = blockIdx.z * kdepth;
  const u16* ga = A + (size_t)(m0 + srow) * lda + kz + (scol << 3);
  const u16* gb = BT + (size_t)(n0 + srow) * lda + kz + (scol << 3);
  const int cb = wid << 9;  // wave-uniform LDS chunk base (u16 units)

  auto stage = [&](int buf, int k0) {
    u16* la = &As[buf][cb];
    u16* lb = &Bs[buf][cb];
    gload_lds16(ga + k0, la);
    gload_lds16(ga + (size_t)64 * lda + k0, la + 2048);
    gload_lds16(gb + k0, lb);
    gload_lds16(gb + (size_t)64 * lda + k0, lb + 2048);
  };

  const int nk = kdepth >> 5;
  stage(0, 0);
  stage(1, 32);

  const int ab = (wid >> 1) << 2, bb = (wid & 1) << 2;  // 16-row block bases
  const int foff = (fr << 5) + ((((fg + (fr >> 1)) & 3)) << 3);
  int cur = 0;
  for (int t = 0; t < nk; ++t) {
    if (t + 2 < nk) {
      int nb = cur + 2; if (nb >= 3) nb -= 3;
      stage(nb, (t + 2) << 5);
      asm volatile("s_waitcnt vmcnt(8)" ::: "memory");   // tile t retired; t+1,t+2 in flight
    } else if (t + 2 == nk) {
      asm volatile("s_waitcnt vmcnt(4)" ::: "memory");
    } else {
      asm volatile("s_waitcnt vmcnt(0)" ::: "memory");
    }
    __builtin_amdgcn_s_barrier();  // all waves' tile-t writes visible
    s16x8 af[4], bq[4];
#pragma unroll
    for (int i = 0; i < 4; ++i) {
      af[i] = *(const s16x8*)(&As[cur][((ab + i) << 9) + foff]);
      bq[i] = *(const s16x8*)(&Bs[cur][((bb + i) << 9) + foff]);
    }
#pragma unroll
    for (int mi = 0; mi < 4; ++mi)
#pragma unroll
      for (int ni = 0; ni < 4; ++ni)
        acc[mi][ni] = __builtin_amdgcn_mfma_f32_16x16x32_bf16(af[mi], bq[ni], acc[mi][ni], 0, 0, 0);
    __builtin_amdgcn_s_barrier();  // reads of buf(t) done before t+3 overwrites
    if (++cur == 3) cur = 0;
  }

#pragma unroll
  for (int mi = 0; mi < 4; ++mi) {
#pragma unroll
    for (int ni = 0; ni < 4; ++ni) {
#pragma unroll
      for (int r = 0; r < 4; ++r) {
        int row = m0 + wm + mi * 16 + fg * 4 + r;
        int col = n0 + wn + ni * 16 + fr;
        size_t off = (size_t)row * ldc + col;
        float v = acc[mi][ni][r];
        if (EPI == 0) ((float*)Cp)[off] = v;
        else if (EPI == 2) ((u16*)Cp)[off] = f2b(v);
        else atomicAdd((float*)Cp + off, v);
      }
    }
  }
}

// ---------------- 256x128 bf16 MFMA GEMM (big-N: lm_head, h13) ----------------
// 512 threads / 8 waves (4M x 2N, 64x64 out each): 16 waves/CU = 4 waves/SIMD.
// Depth-2 3-buffer counted-vmcnt schedule (r12 verified best); 3 loads/wave/stage.
// EPI: 0 = f32 store, 3 = fused SwiGLU (interleaved W13 pack; even lanes write
// silu(h1)*h3 bf16 to g, ldc = 2752).
template <int EPI>
__global__ __launch_bounds__(512, 4) void k_gemm2(const u16* __restrict__ A,
                                                  const u16* __restrict__ BT,
                                                  void* __restrict__ Cp, int K, int ldc) {
  __shared__ u16 As[3][8192];  // [16 blocks16][512 u16] x 3
  __shared__ u16 Bs[3][4096];  // [8 blocks16]
  const int tid = threadIdx.x;
  const int lane = tid & 63, wid = tid >> 6;  // 8 waves
  const int lin = blockIdx.y * gridDim.x + blockIdx.x;  // gridDim.x == 8
  const int cpx = (gridDim.x * gridDim.y) >> 3;
  const int swz = (lin & 7) * cpx + (lin >> 3);
  const int m0 = (swz & 7) << 8, n0 = (swz >> 3) << 7;
  const int fr = lane & 15, fg = lane >> 4;

  f32x4 acc[4][4] = {};

  const int srow = lane >> 2;  // 0..15 within a 16-row block
  const int scol = ((lane & 3) - ((lane >> 3) & 3)) & 3;
  // wave w stages A rows [32w,32w+32) -> blocks 2w,2w+1 ; B rows [16w,16w+16) -> block w
  const u16* ga = A + (size_t)(m0 + (wid << 5) + srow) * K + (scol << 3);
  const u16* gb = BT + (size_t)(n0 + (wid << 4) + srow) * K + (scol << 3);
  const int cba = wid << 10;  // 2 blocks * 512 u16
  const int cbb = wid << 9;   // 1 block * 512 u16

  auto stage = [&](int buf, int k0) {
    gload_lds16(ga + k0, &As[buf][cba]);
    gload_lds16(ga + (size_t)16 * K + k0, &As[buf][cba + 512]);
    gload_lds16(gb + k0, &Bs[buf][cbb]);
  };

  const int nk = K >> 5;
  stage(0, 0);
  stage(1, 32);

  const int am = (wid >> 1) << 2;  // A block base: wave M-group * 4
  const int bn = (wid & 1) << 2;   // B block base: wave N-group * 4
  const int foff = (fr << 5) + ((((fg + (fr >> 1)) & 3)) << 3);
  int cur = 0;
  for (int t = 0; t < nk; ++t) {
    if (t + 2 < nk) {
      int nb = cur + 2; if (nb >= 3) nb -= 3;
      stage(nb, (t + 2) << 5);
      asm volatile("s_waitcnt vmcnt(6)" ::: "memory");  // tile t retired; t+1,t+2 in flight
    } else if (t + 2 == nk) {
      asm volatile("s_waitcnt vmcnt(3)" ::: "memory");
    } else {
      asm volatile("s_waitcnt vmcnt(0)" ::: "memory");
    }
    __builtin_amdgcn_s_barrier();
    s16x8 af[4], bq[4];
#pragma unroll
    for (int i = 0; i < 4; ++i) {
      af[i] = *(const s16x8*)(&As[cur][((am + i) << 9) + foff]);
      bq[i] = *(const s16x8*)(&Bs[cur][((bn + i) << 9) + foff]);
    }
#pragma unroll
    for (int mi = 0; mi < 4; ++mi)
#pragma unroll
      for (int ni = 0; ni < 4; ++ni)
        acc[mi][ni] = __builtin_amdgcn_mfma_f32_16x16x32_bf16(af[mi], bq[ni], acc[mi][ni], 0, 0, 0);
    __builtin_amdgcn_s_barrier();
    if (++cur == 3) cur = 0;
  }

#pragma unroll
  for (int mi = 0; mi < 4; ++mi) {
#pragma unroll
    for (int ni = 0; ni < 4; ++ni) {
#pragma unroll
      for (int r = 0; r < 4; ++r) {
        int row = m0 + ((wid >> 1) << 6) + mi * 16 + fg * 4 + r;
        int col = n0 + ((wid & 1) << 6) + ni * 16 + fr;
        float v = acc[mi][ni][r];
        if (EPI == 0) {
          ((float*)Cp)[(size_t)row * ldc + col] = v;
        } else {  // EPI == 3: fused SwiGLU
          float o = __shfl_xor(v, 1, 64);  // partner col (h1<->h3)
          if (!(fr & 1)) {
            float s = v / (1.0f + __expf(-v)) * o;
            ((u16*)Cp)[(size_t)row * ldc + (col >> 1)] = f2b(s);
          }
        }
      }
    }
  }
}

// ---------------- flash attention: 1 wave = 16 q-rows, KV tiles of 32 -----------
__global__ __launch_bounds__(256) void k_attn(const u16* __restrict__ qh,
                                              const u16* __restrict__ kh,
                                              const u16* __restrict__ vth,
                                              u16* __restrict__ attno, int isGlobal) {
  __shared__ u16 pb[4][512];  // per-wave P tile [16][32]
  const int qblk = blockIdx.x, hq = blockIdx.y, b = blockIdx.z;
  const int lane = threadIdx.x & 63, wid = threadIdx.x >> 6;
  const int fr = lane & 15, fg = lane >> 4;
  const int q0 = (qblk << 6) + (wid << 4);
  const int hk = hq >> 2;  // GQA: 4 q-heads per kv-head
  const u16* Q = qh + ((size_t)(b * HQ_ + hq) * S_) * HD_;
  const u16* Kh = kh + ((size_t)(b * HKV_ + hk) * S_) * HD_;
  const u16* VT = vth + ((size_t)(b * HKV_ + hk) * HD_) * S_;
  u16* pbuf = pb[wid];

  const s16x8 aq0 = *(const s16x8*)(Q + (q0 + fr) * HD_ + fg * 8);
  const s16x8 aq1 = *(const s16x8*)(Q + (q0 + fr) * HD_ + 32 + fg * 8);

  f32x4 o0 = {}, o1 = {}, o2 = {}, o3 = {};
  float m[4], l[4];
#pragma unroll
  for (int r = 0; r < 4; ++r) { m[r] = -1e30f; l[r] = 0.0f; }

  int kt0 = 0;
  if (!isGlobal) { int lo = q0 - (WINDOW_ - 1); if (lo > 0) kt0 = lo & ~31; }
  const int ktend = q0 + 16;

  for (int kt = kt0; kt < ktend; kt += 32) {
    // QK^T: scores [16 q][32 k] in two 16x16 accumulators
    f32x4 sc0 = {}, sc1 = {};
    {
      s16x8 b0 = *(const s16x8*)(Kh + (kt + fr) * HD_ + fg * 8);
      s16x8 b1 = *(const s16x8*)(Kh + (kt + fr) * HD_ + 32 + fg * 8);
      sc0 = __builtin_amdgcn_mfma_f32_16x16x32_bf16(aq0, b0, sc0, 0, 0, 0);
      sc0 = __builtin_amdgcn_mfma_f32_16x16x32_bf16(aq1, b1, sc0, 0, 0, 0);
      s16x8 c0 = *(const s16x8*)(Kh + (kt + 16 + fr) * HD_ + fg * 8);
      s16x8 c1 = *(const s16x8*)(Kh + (kt + 16 + fr) * HD_ + 32 + fg * 8);
      sc1 = __builtin_amdgcn_mfma_f32_16x16x32_bf16(aq0, c0, sc1, 0, 0, 0);
      sc1 = __builtin_amdgcn_mfma_f32_16x16x32_bf16(aq1, c1, sc1, 0, 0, 0);
    }
#pragma unroll
    for (int r = 0; r < 4; ++r) {
      int row = q0 + fg * 4 + r;
      int col0 = kt + fr, col1 = kt + 16 + fr;
      bool v0 = (col0 <= row) && (isGlobal || (row - col0) < WINDOW_);
      bool v1 = (col1 <= row) && (isGlobal || (row - col1) < WINDOW_);
      float s0 = v0 ? sc0[r] * 0.125f : -1e30f;
      float s1 = v1 ? sc1[r] * 0.125f : -1e30f;
      float t = fmaxf(s0, s1);
#pragma unroll
      for (int msk = 1; msk < 16; msk <<= 1) t = fmaxf(t, __shfl_xor(t, msk, 16));
      float mn = fmaxf(m[r], t);
      float fsc = __expf(m[r] - mn);  // -1e30 sentinel keeps this finite (exp(0)=1)
      m[r] = mn;
      float p0 = v0 ? __expf(s0 - mn) : 0.0f;  // mask by select, never by exp(-inf)
      float p1 = v1 ? __expf(s1 - mn) : 0.0f;
      float ps = p0 + p1;
#pragma unroll
      for (int msk = 1; msk < 16; msk <<= 1) ps += __shfl_xor(ps, msk, 16);
      l[r] = l[r] * fsc + ps;
      o0[r] *= fsc; o1[r] *= fsc; o2[r] *= fsc; o3[r] *= fsc;
      pbuf[(fg * 4 + r) * 32 + fr] = f2b(p0);
      pbuf[(fg * 4 + r) * 32 + 16 + fr] = f2b(p1);
    }
    // PV: P (from per-wave LDS, A-fragment layout) x V^T rows
    s16x8 ap = *(const s16x8*)(pbuf + fr * 32 + fg * 8);
    {
      s16x8 bv0 = *(const s16x8*)(VT + (size_t)(0 + fr) * S_ + kt + fg * 8);
      o0 = __builtin_amdgcn_mfma_f32_16x16x32_bf16(ap, bv0, o0, 0, 0, 0);
      s16x8 bv1 = *(const s16x8*)(VT + (size_t)(16 + fr) * S_ + kt + fg * 8);
      o1 = __builtin_amdgcn_mfma_f32_16x16x32_bf16(ap, bv1, o1, 0, 0, 0);
      s16x8 bv2 = *(const s16x8*)(VT + (size_t)(32 + fr) * S_ + kt + fg * 8);
      o2 = __builtin_amdgcn_mfma_f32_16x16x32_bf16(ap, bv2, o2, 0, 0, 0);
      s16x8 bv3 = *(const s16x8*)(VT + (size_t)(48 + fr) * S_ + kt + fg * 8);
      o3 = __builtin_amdgcn_mfma_f32_16x16x32_bf16(ap, bv3, o3, 0, 0, 0);
    }
  }

#pragma unroll
  for (int r = 0; r < 4; ++r) {
    int row = q0 + fg * 4 + r;
    float inv = 1.0f / l[r];
    size_t base = ((size_t)b * S_ + row) * (HQ_ * HD_) + hq * HD_;
    attno[base + fr] = f2b(o0[r] * inv);
    attno[base + 16 + fr] = f2b(o1[r] * inv);
    attno[base + 32 + fr] = f2b(o2[r] * inv);
    attno[base + 48 + fr] = f2b(o3[r] * inv);
  }
}

extern "C" void kernel_launch(void* const* d_in, const int* in_sizes, int n_in,
                              void* d_out, int out_size, void* d_ws, size_t ws_size,
                              hipStream_t stream) {
  (void)in_sizes; (void)n_in; (void)out_size; (void)ws_size;
  const int* idx = (const int*)d_in[0];
  const float* emb = (const float*)d_in[1];
  const float* Wq = (const float*)d_in[2];
  const float* Wk = (const float*)d_in[3];
  const float* Wv = (const float*)d_in[4];
  const float* Wo = (const float*)d_in[5];
  const float* w1 = (const float*)d_in[6];
  const float* w3 = (const float*)d_in[7];
  const float* w2 = (const float*)d_in[8];
  const float* n1 = (const float*)d_in[9];
  const float* n2 = (const float*)d_in[10];
  const float* nf = (const float*)d_in[11];
  float* out = (float*)d_out;

  char* p = (char*)d_ws;
  auto carve = [&](size_t bytes) {
    char* q = p;
    p += (bytes + 255) & ~(size_t)255;
    return (void*)q;
  };
  float* x = (float*)carve((size_t)BS_ * D_ * 4);
  u16* h = (u16*)carve((size_t)BS_ * D_ * 2);
  u16* qkvb = (u16*)carve((size_t)BS_ * 1536 * 2);
  u16* qh = (u16*)carve((size_t)B_ * HQ_ * S_ * HD_ * 2);
  u16* khb = (u16*)carve((size_t)B_ * HKV_ * S_ * HD_ * 2);
  u16* vth = (u16*)carve((size_t)B_ * HKV_ * HD_ * S_ * 2);
  u16* attno = (u16*)carve((size_t)BS_ * D_ * 2);
  u16* g = (u16*)carve((size_t)BS_ * H_ * 2);
  u16* wT = (u16*)carve((size_t)11075584 * 2);
  float* cosT = (float*)carve((size_t)S_ * 32 * 4);
  float* sinT = (float*)carve((size_t)S_ * 32 * 4);
  u16* embb = (u16*)carve((size_t)V_ * D_ * 2);

  // startup: emb->bf16, rope tables, token-embedding gather (single launch)
  k_init<<<32000 + 128 + BS_, 256, 0, stream>>>(emb, embb, cosT, sinT, idx, x);

  for (int l = 0; l < L_; ++l) {
    T7 t7;
    t7.m[0] = { Wq + (size_t)l * D_ * 1024, wT, D_, 1024, 0, 1, 0 };
    t7.m[1] = { Wk + (size_t)l * D_ * 256, wT + 1048576, D_, 256, 1024, 1, 0 };
    t7.m[2] = { Wv + (size_t)l * D_ * 256, wT + 1310720, D_, 256, 1280, 1, 0 };
    t7.m[3] = { Wo + (size_t)l * 1024 * D_, wT + 1572864, 1024, D_, 1536, 1, 0 };
    // W1/W3 interleaved: w1 col j -> row 2j, w3 col j -> row 2j+1 (fused silu)
    t7.m[4] = { w1 + (size_t)l * D_ * H_, wT + 2621440, D_, H_, 2560, 2, 0 };
    t7.m[5] = { w3 + (size_t)l * D_ * H_, wT + 2621440, D_, H_, 5312, 2, 1 };
    t7.m[6] = { w2 + (size_t)l * H_ * D_, wT + 8257536, H_, D_, 8064, 1, 0 };

    // fused: weight pack transpose + rmsnorm1 (one launch)
    k_tr_rms<<<10816 + BS_, 256, 0, stream>>>(t7, x, n1 + (size_t)l * D_, h);
    // QKV fused: BT = [WqT; WkT; WvT] (N=1536), bf16 out (r23)
    k_gemm<2><<<dim3(16, 12), 256, 0, stream>>>(h, wT, qkvb, 1024, 1024, 1536);
    k_ropev<<<BS_ + 256, 256, 0, stream>>>(qkvb, cosT, sinT, qh, khb, vth);
    int ig = ((l + 1) % 4) == 0;
    k_attn<<<dim3(16, HQ_, B_), 256, 0, stream>>>(qh, khb, vth, attno, ig);
    // x += attno @ Wo  (split-K=2, fp32 atomic accumulate into residual)
    k_gemm<4><<<dim3(16, 8, 2), 256, 0, stream>>>(attno, wT + 1572864, x, 512, 1024, 1024);
    k_rmsnorm<<<BS_, 256, 0, stream>>>(x, n2 + (size_t)l * D_, h);
    // g = silu(h@W1) * (h@W3), fused: interleaved W13 pack, 256x128 tiles
    k_gemm2<3><<<dim3(8, 43), 512, 0, stream>>>(h, wT + 2621440, g, 1024, 2752);
    // x += g @ W2  (split-K=2 atomic)
    k_gemm<4><<<dim3(16, 8, 2), 256, 0, stream>>>(g, wT + 8257536, x, 1376, 2752, 1024);
  }

  k_rmsnorm<<<BS_, 256, 0, stream>>>(x, nf, h);
  // logits = xn @ emb^T  (BT = emb bf16), 256x128 tiles
  k_gemm2<0><<<dim3(8, 250), 512, 0, stream>>>(h, embb, out, 1024, 32000);
}

// Round 24
// 1455.083 us; speedup vs baseline: 1.0254x; 1.0007x over previous
//
#include <hip/hip_runtime.h>

#define V_ 32000
#define D_ 1024
#define L_ 8
#define HQ_ 16
#define HKV_ 4
#define HD_ 64
#define H_ 2752
#define B_ 2
#define S_ 1024
#define BS_ 2048
#define WINDOW_ 256

typedef float f32x4 __attribute__((ext_vector_type(4)));
typedef short s16x8 __attribute__((ext_vector_type(8)));
typedef unsigned short u16;

__device__ __forceinline__ u16 f2b(float f) {
  union { float f; unsigned u; } a; a.f = f;
  return (u16)((a.u + 0x7fffu + ((a.u >> 16) & 1u)) >> 16);
}
__device__ __forceinline__ float b2f(u16 b) {
  union { unsigned u; float f; } a; a.u = ((unsigned)b) << 16; return a.f;
}

// async global->LDS, 16B per lane. LDS dest must be wave-uniform; CK-style casts.
__device__ __forceinline__ void gload_lds16(const void* g, void* l) {
  __builtin_amdgcn_global_load_lds(
      (const __attribute__((address_space(1))) void*)(unsigned long long)(uintptr_t)g,
      (__attribute__((address_space(3))) void*)(unsigned int)(uintptr_t)l,
      16, 0, 0);
}

// ---------------- startup: emb cvt + rope table + embedding gather (1 launch) --
__global__ void k_init(const float* __restrict__ src, u16* __restrict__ dst,
                       float* __restrict__ cosT, float* __restrict__ sinT,
                       const int* __restrict__ idx, float* __restrict__ x) {
  int bid = blockIdx.x;
  if (bid < 32000) {  // cvt: 32000 blocks x 256 thr x float4 = V*D exactly
    long i = (long)bid * 256 + threadIdx.x;
    float4 v = ((const float4*)src)[i];
    ushort4 o; o.x = f2b(v.x); o.y = f2b(v.y); o.z = f2b(v.z); o.w = f2b(v.w);
    ((ushort4*)dst)[i] = o;
  } else if (bid < 32128) {  // ropetab: 128 blocks -> S*32 entries
    int i = (bid - 32000) * 256 + threadIdx.x;
    int s = i >> 5, d = i & 31;
    float inv = __expf(-((float)(2 * d) / (float)HD_) * logf(10000.0f));
    float f = (float)s * inv;
    cosT[i] = cosf(f); sinT[i] = sinf(f);
  } else {  // embed: 2048 blocks
    int t = bid - 32128;
    int token = idx[t];
    const float4* s = (const float4*)(src + (size_t)token * D_);
    float4* d = (float4*)(x + (size_t)t * D_);
    d[threadIdx.x] = s[threadIdx.x];
  }
}

// ---- fused per-layer prep: weight transpose-convert pack + rmsnorm1 (1 launch)
// blocks [0,10816): 7-matrix transpose into bf16 B^T pack (dst row = col*mul+add;
// W1/W3 interleave for the fused-silu epilogue). blocks [10816,10816+2048):
// rmsnorm of x into h. Disjoint outputs (wT vs h); both inputs ready at launch.
// Per-layer launch keeps the pack L2/L3-warm for the GEMMs (r17 lesson).
struct TMat { const float* src; u16* dst; int R, C, t0, mul, add; };
struct T7 { TMat m[7]; };

__global__ void k_tr_rms(T7 P, const float* __restrict__ x,
                         const float* __restrict__ w, u16* __restrict__ out) {
  __shared__ float tile[32][33];
  int bid = blockIdx.x;
  int tid = threadIdx.x;
  if (bid < 10816) {  // transpose path
    int mi = 0;
#pragma unroll
    for (int i = 1; i < 7; ++i) if (bid >= P.m[i].t0) mi = i;
    TMat mm = P.m[mi];
    int tl = bid - mm.t0;
    int ct = mm.C >> 5;
    int tr = tl / ct, tc = tl - tr * ct;
    int r0 = tr << 5, c0 = tc << 5;
    int tx = tid & 31, ty = tid >> 5;
#pragma unroll
    for (int j = 0; j < 4; ++j)
      tile[ty + j * 8][tx] = mm.src[(size_t)(r0 + ty + j * 8) * mm.C + c0 + tx];
    __syncthreads();
#pragma unroll
    for (int j = 0; j < 4; ++j)
      mm.dst[((size_t)(c0 + ty + j * 8) * mm.mul + mm.add) * mm.R + r0 + tx] =
          f2b(tile[tx][ty + j * 8]);
  } else {  // rmsnorm path
    int row = bid - 10816;
    float4 v = ((const float4*)(x + (size_t)row * D_))[tid];
    float ss = v.x * v.x + v.y * v.y + v.z * v.z + v.w * v.w;
#pragma unroll
    for (int m = 1; m < 64; m <<= 1) ss += __shfl_xor(ss, m, 64);
    if ((tid & 63) == 0) tile[0][tid >> 6] = ss;
    __syncthreads();
    float tot = tile[0][0] + tile[0][1] + tile[0][2] + tile[0][3];
    float rs = rsqrtf(tot * (1.0f / D_) + 1e-6f);
    float4 wv = ((const float4*)w)[tid];
    ushort4 o;
    o.x = f2b(v.x * rs * wv.x); o.y = f2b(v.y * rs * wv.y);
    o.z = f2b(v.z * rs * wv.z); o.w = f2b(v.w * rs * wv.w);
    ((ushort4*)(out + (size_t)row * D_))[tid] = o;
  }
}

// ---------------- rmsnorm (fp32 in) -> bf16 out ----------------
__global__ void k_rmsnorm(const float* __restrict__ x, const float* __restrict__ w,
                          u16* __restrict__ out) {
  int row = blockIdx.x, tid = threadIdx.x;
  float4 v = ((const float4*)(x + (size_t)row * D_))[tid];
  float ss = v.x * v.x + v.y * v.y + v.z * v.z + v.w * v.w;
#pragma unroll
  for (int m = 1; m < 64; m <<= 1) ss += __shfl_xor(ss, m, 64);
  __shared__ float red[4];
  if ((tid & 63) == 0) red[tid >> 6] = ss;
  __syncthreads();
  float tot = red[0] + red[1] + red[2] + red[3];
  float rs = rsqrtf(tot * (1.0f / D_) + 1e-6f);
  float4 wv = ((const float4*)w)[tid];
  ushort4 o;
  o.x = f2b(v.x * rs * wv.x); o.y = f2b(v.y * rs * wv.y);
  o.z = f2b(v.z * rs * wv.z); o.w = f2b(v.w * rs * wv.w);
  ((ushort4*)(out + (size_t)row * D_))[tid] = o;
}

// ---------------- fused rope (q,k) + V transpose; one launch/layer ------------
// qkvb is the bf16 qkv GEMM output (r23: halves the fp32 round-trip traffic;
// RoPE on bf16-rounded q/k adds one quantization, ~0.2% rel, V path exact).
__global__ void k_ropev(const u16* __restrict__ qkvb, const float* __restrict__ cosT,
                        const float* __restrict__ sinT, u16* __restrict__ qh,
                        u16* __restrict__ kh, u16* __restrict__ vth) {
  __shared__ float tile[32][65];
  int bid = blockIdx.x;
  int tid = threadIdx.x;
  if (bid < BS_) {  // RoPE: q + k head-major
    int t = bid;
    int b = t >> 10, s = t & (S_ - 1);
    const u16* row = qkvb + (size_t)t * 1536;
    for (int p = tid; p < 512; p += 256) {           // q: 512 pairs
      int hh = p >> 5, d = p & 31;
      float x0 = b2f(row[hh * 64 + 2 * d]), x1 = b2f(row[hh * 64 + 2 * d + 1]);
      float c = cosT[s * 32 + d], sn = sinT[s * 32 + d];
      size_t o = ((size_t)(b * HQ_ + hh) * S_ + s) * HD_ + 2 * d;
      qh[o] = f2b(x0 * c - x1 * sn);
      qh[o + 1] = f2b(x0 * sn + x1 * c);
    }
    if (tid < 128) {                                  // k: 128 pairs
      int hh = tid >> 5, d = tid & 31;
      float x0 = b2f(row[1024 + hh * 64 + 2 * d]), x1 = b2f(row[1024 + hh * 64 + 2 * d + 1]);
      float c = cosT[s * 32 + d], sn = sinT[s * 32 + d];
      size_t o = ((size_t)(b * HKV_ + hh) * S_ + s) * HD_ + 2 * d;
      kh[o] = f2b(x0 * c - x1 * sn);
      kh[o + 1] = f2b(x0 * sn + x1 * c);
    }
  } else {  // V transpose -> vth [b][kvh][64][S] (bf16->f32->bf16 is exact)
    int v = bid - BS_;                // 0..255
    const int s0 = (v & 31) << 5, hh = (v >> 5) & 3, b = v >> 7;
    const int tx = tid & 63, ty = tid >> 6;  // load: 64 d x 4 s-rows
#pragma unroll
    for (int j = 0; j < 8; ++j) {
      int sl = j * 4 + ty;
      tile[sl][tx] = b2f(qkvb[(size_t)((b << 10) + s0 + sl) * 1536 + 1280 + hh * 64 + tx]);
    }
    __syncthreads();
    const int sx = tid & 31, dr = tid >> 5;  // store: 32 s x 8 d-rows
#pragma unroll
    for (int j = 0; j < 8; ++j) {
      int d = j * 8 + dr;
      vth[((size_t)((b * HKV_ + hh) << 6) + d) * S_ + s0 + sx] = f2b(tile[sx][d]);
    }
  }
}

// ---------------- 128x128 bf16 MFMA GEMM: C = A[M,*] @ BT[N,*]^T ----------------
// Depth-2 prefetch, 3-buffer rotation, counted vmcnt (r9/r10/r12 verified best).
// kdepth = K handled by this block (split-K via blockIdx.z); lda = row stride.
// EPI: 0 = f32 store, 2 = bf16 store, 4 = fp32 atomicAdd (split-K accumulate)
template <int EPI>
__global__ __launch_bounds__(256) void k_gemm(const u16* __restrict__ A,
                                              const u16* __restrict__ BT,
                                              void* __restrict__ Cp, int kdepth,
                                              int lda, int ldc) {
  __shared__ u16 As[3][4096];  // [8 blocks16][64 slots][8 u16] x 3 buffers
  __shared__ u16 Bs[3][4096];
  const int tid = threadIdx.x;
  const int lane = tid & 63, wid = tid >> 6;
  const int lin = blockIdx.y * 16 + blockIdx.x;
  const int cpx = (gridDim.x * gridDim.y) >> 3;
  const int swz = (lin & 7) * cpx + (lin >> 3);
  const int m0 = (swz & 15) << 7, n0 = (swz >> 4) << 7;
  const int wm = (wid >> 1) << 6, wn = (wid & 1) << 6;
  const int fr = lane & 15, fg = lane >> 4;

  f32x4 acc[4][4] = {};

  const int srow = (wid << 4) + (lane >> 2);
  const int scol = ((lane & 3) - ((lane >> 3) & 3)) & 3;
  const int kz = blockIdx.z * kdepth;
  const u16* ga = A + (size_t)(m0 + srow) * lda + kz + (scol << 3);
  const u16* gb = BT + (size_t)(n0 + srow) * lda + kz + (scol << 3);
  const int cb = wid << 9;  // wave-uniform LDS chunk base (u16 units)

  auto stage = [&](int buf, int k0) {
    u16* la = &As[buf][cb];
    u16* lb = &Bs[buf][cb];
    gload_lds16(ga + k0, la);
    gload_lds16(ga + (size_t)64 * lda + k0, la + 2048);
    gload_lds16(gb + k0, lb);
    gload_lds16(gb + (size_t)64 * lda + k0, lb + 2048);
  };

  const int nk = kdepth >> 5;
  stage(0, 0);
  stage(1, 32);

  const int ab = (wid >> 1) << 2, bb = (wid & 1) << 2;  // 16-row block bases
  const int foff = (fr << 5) + ((((fg + (fr >> 1)) & 3)) << 3);
  int cur = 0;
  for (int t = 0; t < nk; ++t) {
    if (t + 2 < nk) {
      int nb = cur + 2; if (nb >= 3) nb -= 3;
      stage(nb, (t + 2) << 5);
      asm volatile("s_waitcnt vmcnt(8)" ::: "memory");   // tile t retired; t+1,t+2 in flight
    } else if (t + 2 == nk) {
      asm volatile("s_waitcnt vmcnt(4)" ::: "memory");
    } else {
      asm volatile("s_waitcnt vmcnt(0)" ::: "memory");
    }
    __builtin_amdgcn_s_barrier();  // all waves' tile-t writes visible
    s16x8 af[4], bq[4];
#pragma unroll
    for (int i = 0; i < 4; ++i) {
      af[i] = *(const s16x8*)(&As[cur][((ab + i) << 9) + foff]);
      bq[i] = *(const s16x8*)(&Bs[cur][((bb + i) << 9) + foff]);
    }
#pragma unroll
    for (int mi = 0; mi < 4; ++mi)
#pragma unroll
      for (int ni = 0; ni < 4; ++ni)
        acc[mi][ni] = __builtin_amdgcn_mfma_f32_16x16x32_bf16(af[mi], bq[ni], acc[mi][ni], 0, 0, 0);
    __builtin_amdgcn_s_barrier();  // reads of buf(t) done before t+3 overwrites
    if (++cur == 3) cur = 0;
  }

#pragma unroll
  for (int mi = 0; mi < 4; ++mi) {
#pragma unroll
    for (int ni = 0; ni < 4; ++ni) {
#pragma unroll
      for (int r = 0; r < 4; ++r) {
        int row = m0 + wm + mi * 16 + fg * 4 + r;
        int col = n0 + wn + ni * 16 + fr;
        size_t off = (size_t)row * ldc + col;
        float v = acc[mi][ni][r];
        if (EPI == 0) ((float*)Cp)[off] = v;
        else if (EPI == 2) ((u16*)Cp)[off] = f2b(v);
        else atomicAdd((float*)Cp + off, v);
      }
    }
  }
}

// ---------------- 256x128 bf16 MFMA GEMM (big-N: lm_head, h13) ----------------
// 512 threads / 8 waves (4M x 2N, 64x64 out each): 16 waves/CU = 4 waves/SIMD.
// Depth-2 3-buffer counted-vmcnt schedule (r12 verified best); 3 loads/wave/stage.
// EPI: 0 = f32 store, 3 = fused SwiGLU (interleaved W13 pack; even lanes write
// silu(h1)*h3 bf16 to g, ldc = 2752).
template <int EPI>
__global__ __launch_bounds__(512, 4) void k_gemm2(const u16* __restrict__ A,
                                                  const u16* __restrict__ BT,
                                                  void* __restrict__ Cp, int K, int ldc) {
  __shared__ u16 As[3][8192];  // [16 blocks16][512 u16] x 3
  __shared__ u16 Bs[3][4096];  // [8 blocks16]
  const int tid = threadIdx.x;
  const int lane = tid & 63, wid = tid >> 6;  // 8 waves
  const int lin = blockIdx.y * gridDim.x + blockIdx.x;  // gridDim.x == 8
  const int cpx = (gridDim.x * gridDim.y) >> 3;
  const int swz = (lin & 7) * cpx + (lin >> 3);
  const int m0 = (swz & 7) << 8, n0 = (swz >> 3) << 7;
  const int fr = lane & 15, fg = lane >> 4;

  f32x4 acc[4][4] = {};

  const int srow = lane >> 2;  // 0..15 within a 16-row block
  const int scol = ((lane & 3) - ((lane >> 3) & 3)) & 3;
  // wave w stages A rows [32w,32w+32) -> blocks 2w,2w+1 ; B rows [16w,16w+16) -> block w
  const u16* ga = A + (size_t)(m0 + (wid << 5) + srow) * K + (scol << 3);
  const u16* gb = BT + (size_t)(n0 + (wid << 4) + srow) * K + (scol << 3);
  const int cba = wid << 10;  // 2 blocks * 512 u16
  const int cbb = wid << 9;   // 1 block * 512 u16

  auto stage = [&](int buf, int k0) {
    gload_lds16(ga + k0, &As[buf][cba]);
    gload_lds16(ga + (size_t)16 * K + k0, &As[buf][cba + 512]);
    gload_lds16(gb + k0, &Bs[buf][cbb]);
  };

  const int nk = K >> 5;
  stage(0, 0);
  stage(1, 32);

  const int am = (wid >> 1) << 2;  // A block base: wave M-group * 4
  const int bn = (wid & 1) << 2;   // B block base: wave N-group * 4
  const int foff = (fr << 5) + ((((fg + (fr >> 1)) & 3)) << 3);
  int cur = 0;
  for (int t = 0; t < nk; ++t) {
    if (t + 2 < nk) {
      int nb = cur + 2; if (nb >= 3) nb -= 3;
      stage(nb, (t + 2) << 5);
      asm volatile("s_waitcnt vmcnt(6)" ::: "memory");  // tile t retired; t+1,t+2 in flight
    } else if (t + 2 == nk) {
      asm volatile("s_waitcnt vmcnt(3)" ::: "memory");
    } else {
      asm volatile("s_waitcnt vmcnt(0)" ::: "memory");
    }
    __builtin_amdgcn_s_barrier();
    s16x8 af[4], bq[4];
#pragma unroll
    for (int i = 0; i < 4; ++i) {
      af[i] = *(const s16x8*)(&As[cur][((am + i) << 9) + foff]);
      bq[i] = *(const s16x8*)(&Bs[cur][((bn + i) << 9) + foff]);
    }
#pragma unroll
    for (int mi = 0; mi < 4; ++mi)
#pragma unroll
      for (int ni = 0; ni < 4; ++ni)
        acc[mi][ni] = __builtin_amdgcn_mfma_f32_16x16x32_bf16(af[mi], bq[ni], acc[mi][ni], 0, 0, 0);
    __builtin_amdgcn_s_barrier();
    if (++cur == 3) cur = 0;
  }

#pragma unroll
  for (int mi = 0; mi < 4; ++mi) {
#pragma unroll
    for (int ni = 0; ni < 4; ++ni) {
#pragma unroll
      for (int r = 0; r < 4; ++r) {
        int row = m0 + ((wid >> 1) << 6) + mi * 16 + fg * 4 + r;
        int col = n0 + ((wid & 1) << 6) + ni * 16 + fr;
        float v = acc[mi][ni][r];
        if (EPI == 0) {
          ((float*)Cp)[(size_t)row * ldc + col] = v;
        } else {  // EPI == 3: fused SwiGLU
          float o = __shfl_xor(v, 1, 64);  // partner col (h1<->h3)
          if (!(fr & 1)) {
            float s = v / (1.0f + __expf(-v)) * o;
            ((u16*)Cp)[(size_t)row * ldc + (col >> 1)] = f2b(s);
          }
        }
      }
    }
  }
}

// ---------------- flash attention: 1 wave = 16 q-rows, KV tiles of 32 -----------
__global__ __launch_bounds__(256) void k_attn(const u16* __restrict__ qh,
                                              const u16* __restrict__ kh,
                                              const u16* __restrict__ vth,
                                              u16* __restrict__ attno, int isGlobal) {
  __shared__ u16 pb[4][512];  // per-wave P tile [16][32]
  const int qblk = blockIdx.x, hq = blockIdx.y, b = blockIdx.z;
  const int lane = threadIdx.x & 63, wid = threadIdx.x >> 6;
  const int fr = lane & 15, fg = lane >> 4;
  const int q0 = (qblk << 6) + (wid << 4);
  const int hk = hq >> 2;  // GQA: 4 q-heads per kv-head
  const u16* Q = qh + ((size_t)(b * HQ_ + hq) * S_) * HD_;
  const u16* Kh = kh + ((size_t)(b * HKV_ + hk) * S_) * HD_;
  const u16* VT = vth + ((size_t)(b * HKV_ + hk) * HD_) * S_;
  u16* pbuf = pb[wid];

  const s16x8 aq0 = *(const s16x8*)(Q + (q0 + fr) * HD_ + fg * 8);
  const s16x8 aq1 = *(const s16x8*)(Q + (q0 + fr) * HD_ + 32 + fg * 8);

  f32x4 o0 = {}, o1 = {}, o2 = {}, o3 = {};
  float m[4], l[4];
#pragma unroll
  for (int r = 0; r < 4; ++r) { m[r] = -1e30f; l[r] = 0.0f; }

  int kt0 = 0;
  if (!isGlobal) { int lo = q0 - (WINDOW_ - 1); if (lo > 0) kt0 = lo & ~31; }
  const int ktend = q0 + 16;

  for (int kt = kt0; kt < ktend; kt += 32) {
    // QK^T: scores [16 q][32 k] in two 16x16 accumulators
    f32x4 sc0 = {}, sc1 = {};
    {
      s16x8 b0 = *(const s16x8*)(Kh + (kt + fr) * HD_ + fg * 8);
      s16x8 b1 = *(const s16x8*)(Kh + (kt + fr) * HD_ + 32 + fg * 8);
      sc0 = __builtin_amdgcn_mfma_f32_16x16x32_bf16(aq0, b0, sc0, 0, 0, 0);
      sc0 = __builtin_amdgcn_mfma_f32_16x16x32_bf16(aq1, b1, sc0, 0, 0, 0);
      s16x8 c0 = *(const s16x8*)(Kh + (kt + 16 + fr) * HD_ + fg * 8);
      s16x8 c1 = *(const s16x8*)(Kh + (kt + 16 + fr) * HD_ + 32 + fg * 8);
      sc1 = __builtin_amdgcn_mfma_f32_16x16x32_bf16(aq0, c0, sc1, 0, 0, 0);
      sc1 = __builtin_amdgcn_mfma_f32_16x16x32_bf16(aq1, c1, sc1, 0, 0, 0);
    }
#pragma unroll
    for (int r = 0; r < 4; ++r) {
      int row = q0 + fg * 4 + r;
      int col0 = kt + fr, col1 = kt + 16 + fr;
      bool v0 = (col0 <= row) && (isGlobal || (row - col0) < WINDOW_);
      bool v1 = (col1 <= row) && (isGlobal || (row - col1) < WINDOW_);
      float s0 = v0 ? sc0[r] * 0.125f : -1e30f;
      float s1 = v1 ? sc1[r] * 0.125f : -1e30f;
      float t = fmaxf(s0, s1);
#pragma unroll
      for (int msk = 1; msk < 16; msk <<= 1) t = fmaxf(t, __shfl_xor(t, msk, 16));
      float mn = fmaxf(m[r], t);
      float fsc = __expf(m[r] - mn);  // -1e30 sentinel keeps this finite (exp(0)=1)
      m[r] = mn;
      float p0 = v0 ? __expf(s0 - mn) : 0.0f;  // mask by select, never by exp(-inf)
      float p1 = v1 ? __expf(s1 - mn) : 0.0f;
      float ps = p0 + p1;
#pragma unroll
      for (int msk = 1; msk < 16; msk <<= 1) ps += __shfl_xor(ps, msk, 16);
      l[r] = l[r] * fsc + ps;
      o0[r] *= fsc; o1[r] *= fsc; o2[r] *= fsc; o3[r] *= fsc;
      pbuf[(fg * 4 + r) * 32 + fr] = f2b(p0);
      pbuf[(fg * 4 + r) * 32 + 16 + fr] = f2b(p1);
    }
    // PV: P (from per-wave LDS, A-fragment layout) x V^T rows
    s16x8 ap = *(const s16x8*)(pbuf + fr * 32 + fg * 8);
    {
      s16x8 bv0 = *(const s16x8*)(VT + (size_t)(0 + fr) * S_ + kt + fg * 8);
      o0 = __builtin_amdgcn_mfma_f32_16x16x32_bf16(ap, bv0, o0, 0, 0, 0);
      s16x8 bv1 = *(const s16x8*)(VT + (size_t)(16 + fr) * S_ + kt + fg * 8);
      o1 = __builtin_amdgcn_mfma_f32_16x16x32_bf16(ap, bv1, o1, 0, 0, 0);
      s16x8 bv2 = *(const s16x8*)(VT + (size_t)(32 + fr) * S_ + kt + fg * 8);
      o2 = __builtin_amdgcn_mfma_f32_16x16x32_bf16(ap, bv2, o2, 0, 0, 0);
      s16x8 bv3 = *(const s16x8*)(VT + (size_t)(48 + fr) * S_ + kt + fg * 8);
      o3 = __builtin_amdgcn_mfma_f32_16x16x32_bf16(ap, bv3, o3, 0, 0, 0);
    }
  }

#pragma unroll
  for (int r = 0; r < 4; ++r) {
    int row = q0 + fg * 4 + r;
    float inv = 1.0f / l[r];
    size_t base = ((size_t)b * S_ + row) * (HQ_ * HD_) + hq * HD_;
    attno[base + fr] = f2b(o0[r] * inv);
    attno[base + 16 + fr] = f2b(o1[r] * inv);
    attno[base + 32 + fr] = f2b(o2[r] * inv);
    attno[base + 48 + fr] = f2b(o3[r] * inv);
  }
}

extern "C" void kernel_launch(void* const* d_in, const int* in_sizes, int n_in,
                              void* d_out, int out_size, void* d_ws, size_t ws_size,
                              hipStream_t stream) {
  (void)in_sizes; (void)n_in; (void)out_size; (void)ws_size;
  const int* idx = (const int*)d_in[0];
  const float* emb = (const float*)d_in[1];
  const float* Wq = (const float*)d_in[2];
  const float* Wk = (const float*)d_in[3];
  const float* Wv = (const float*)d_in[4];
  const float* Wo = (const float*)d_in[5];
  const float* w1 = (const float*)d_in[6];
  const float* w3 = (const float*)d_in[7];
  const float* w2 = (const float*)d_in[8];
  const float* n1 = (const float*)d_in[9];
  const float* n2 = (const float*)d_in[10];
  const float* nf = (const float*)d_in[11];
  float* out = (float*)d_out;

  char* p = (char*)d_ws;
  auto carve = [&](size_t bytes) {
    char* q = p;
    p += (bytes + 255) & ~(size_t)255;
    return (void*)q;
  };
  float* x = (float*)carve((size_t)BS_ * D_ * 4);
  u16* h = (u16*)carve((size_t)BS_ * D_ * 2);
  u16* qkvb = (u16*)carve((size_t)BS_ * 1536 * 2);
  u16* qh = (u16*)carve((size_t)B_ * HQ_ * S_ * HD_ * 2);
  u16* khb = (u16*)carve((size_t)B_ * HKV_ * S_ * HD_ * 2);
  u16* vth = (u16*)carve((size_t)B_ * HKV_ * HD_ * S_ * 2);
  u16* attno = (u16*)carve((size_t)BS_ * D_ * 2);
  u16* g = (u16*)carve((size_t)BS_ * H_ * 2);
  u16* wT = (u16*)carve((size_t)11075584 * 2);
  float* cosT = (float*)carve((size_t)S_ * 32 * 4);
  float* sinT = (float*)carve((size_t)S_ * 32 * 4);
  u16* embb = (u16*)carve((size_t)V_ * D_ * 2);

  // startup: emb->bf16, rope tables, token-embedding gather (single launch)
  k_init<<<32000 + 128 + BS_, 256, 0, stream>>>(emb, embb, cosT, sinT, idx, x);

  for (int l = 0; l < L_; ++l) {
    T7 t7;
    t7.m[0] = { Wq + (size_t)l * D_ * 1024, wT, D_, 1024, 0, 1, 0 };
    t7.m[1] = { Wk + (size_t)l * D_ * 256, wT + 1048576, D_, 256, 1024, 1, 0 };
    t7.m[2] = { Wv + (size_t)l * D_ * 256, wT + 1310720, D_, 256, 1280, 1, 0 };
    t7.m[3] = { Wo + (size_t)l * 1024 * D_, wT + 1572864, 1024, D_, 1536, 1, 0 };
    // W1/W3 interleaved: w1 col j -> row 2j, w3 col j -> row 2j+1 (fused silu)
    t7.m[4] = { w1 + (size_t)l * D_ * H_, wT + 2621440, D_, H_, 2560, 2, 0 };
    t7.m[5] = { w3 + (size_t)l * D_ * H_, wT + 2621440, D_, H_, 5312, 2, 1 };
    t7.m[6] = { w2 + (size_t)l * H_ * D_, wT + 8257536, H_, D_, 8064, 1, 0 };

    // fused: weight pack transpose + rmsnorm1 (one launch)
    k_tr_rms<<<10816 + BS_, 256, 0, stream>>>(t7, x, n1 + (size_t)l * D_, h);
    // QKV fused: BT = [WqT; WkT; WvT] (N=1536), bf16 out (r23)
    k_gemm<2><<<dim3(16, 12), 256, 0, stream>>>(h, wT, qkvb, 1024, 1024, 1536);
    k_ropev<<<BS_ + 256, 256, 0, stream>>>(qkvb, cosT, sinT, qh, khb, vth);
    int ig = ((l + 1) % 4) == 0;
    k_attn<<<dim3(16, HQ_, B_), 256, 0, stream>>>(qh, khb, vth, attno, ig);
    // x += attno @ Wo  (split-K=2, fp32 atomic accumulate into residual)
    k_gemm<4><<<dim3(16, 8, 2), 256, 0, stream>>>(attno, wT + 1572864, x, 512, 1024, 1024);
    k_rmsnorm<<<BS_, 256, 0, stream>>>(x, n2 + (size_t)l * D_, h);
    // g = silu(h@W1) * (h@W3), fused: interleaved W13 pack, 256x128 tiles
    k_gemm2<3><<<dim3(8, 43), 512, 0, stream>>>(h, wT + 2621440, g, 1024, 2752);
    // x += g @ W2  (split-K=2 atomic)
    k_gemm<4><<<dim3(16, 8, 2), 256, 0, stream>>>(g, wT + 8257536, x, 1376, 2752, 1024);
  }

  k_rmsnorm<<<BS_, 256, 0, stream>>>(x, nf, h);
  // logits = xn @ emb^T  (BT = emb bf16), 256x128 tiles
  k_gemm2<0><<<dim3(8, 250), 512, 0, stream>>>(h, embb, out, 1024, 32000);
}

// Round 25
// 1453.468 us; speedup vs baseline: 1.0266x; 1.0011x over previous
//
#include <hip/hip_runtime.h>

#define V_ 32000
#define D_ 1024
#define L_ 8
#define HQ_ 16
#define HKV_ 4
#define HD_ 64
#define H_ 2752
#define B_ 2
#define S_ 1024
#define BS_ 2048
#define WINDOW_ 256

typedef float f32x4 __attribute__((ext_vector_type(4)));
typedef short s16x8 __attribute__((ext_vector_type(8)));
typedef unsigned short u16;

__device__ __forceinline__ u16 f2b(float f) {
  union { float f; unsigned u; } a; a.f = f;
  return (u16)((a.u + 0x7fffu + ((a.u >> 16) & 1u)) >> 16);
}
__device__ __forceinline__ float b2f(u16 b) {
  union { unsigned u; float f; } a; a.u = ((unsigned)b) << 16; return a.f;
}

// async global->LDS, 16B per lane. LDS dest must be wave-uniform; CK-style casts.
__device__ __forceinline__ void gload_lds16(const void* g, void* l) {
  __builtin_amdgcn_global_load_lds(
      (const __attribute__((address_space(1))) void*)(unsigned long long)(uintptr_t)g,
      (__attribute__((address_space(3))) void*)(unsigned int)(uintptr_t)l,
      16, 0, 0);
}

// ---------------- startup: emb cvt + rope table + embedding gather (1 launch) --
__global__ void k_init(const float* __restrict__ src, u16* __restrict__ dst,
                       float* __restrict__ cosT, float* __restrict__ sinT,
                       const int* __restrict__ idx, float* __restrict__ x) {
  int bid = blockIdx.x;
  if (bid < 32000) {  // cvt: 32000 blocks x 256 thr x float4 = V*D exactly
    long i = (long)bid * 256 + threadIdx.x;
    float4 v = ((const float4*)src)[i];
    ushort4 o; o.x = f2b(v.x); o.y = f2b(v.y); o.z = f2b(v.z); o.w = f2b(v.w);
    ((ushort4*)dst)[i] = o;
  } else if (bid < 32128) {  // ropetab: 128 blocks -> S*32 entries
    int i = (bid - 32000) * 256 + threadIdx.x;
    int s = i >> 5, d = i & 31;
    float inv = __expf(-((float)(2 * d) / (float)HD_) * logf(10000.0f));
    float f = (float)s * inv;
    cosT[i] = cosf(f); sinT[i] = sinf(f);
  } else {  // embed: 2048 blocks
    int t = bid - 32128;
    int token = idx[t];
    const float4* s = (const float4*)(src + (size_t)token * D_);
    float4* d = (float4*)(x + (size_t)t * D_);
    d[threadIdx.x] = s[threadIdx.x];
  }
}

// ---- fused per-layer prep: weight transpose-convert pack + rmsnorm1 (1 launch)
// blocks [0,10816): 7-matrix transpose into bf16 B^T pack (dst row = col*mul+add;
// W1/W3 interleave for the fused-silu epilogue). blocks [10816,10816+2048):
// rmsnorm of x into h. Disjoint outputs (wT vs h); both inputs ready at launch.
// Per-layer launch keeps the pack L2/L3-warm for the GEMMs (r17 lesson).
struct TMat { const float* src; u16* dst; int R, C, t0, mul, add; };
struct T7 { TMat m[7]; };

__global__ void k_tr_rms(T7 P, const float* __restrict__ x,
                         const float* __restrict__ w, u16* __restrict__ out) {
  __shared__ float tile[32][33];
  int bid = blockIdx.x;
  int tid = threadIdx.x;
  if (bid < 10816) {  // transpose path
    int mi = 0;
#pragma unroll
    for (int i = 1; i < 7; ++i) if (bid >= P.m[i].t0) mi = i;
    TMat mm = P.m[mi];
    int tl = bid - mm.t0;
    int ct = mm.C >> 5;
    int tr = tl / ct, tc = tl - tr * ct;
    int r0 = tr << 5, c0 = tc << 5;
    int tx = tid & 31, ty = tid >> 5;
#pragma unroll
    for (int j = 0; j < 4; ++j)
      tile[ty + j * 8][tx] = mm.src[(size_t)(r0 + ty + j * 8) * mm.C + c0 + tx];
    __syncthreads();
#pragma unroll
    for (int j = 0; j < 4; ++j)
      mm.dst[((size_t)(c0 + ty + j * 8) * mm.mul + mm.add) * mm.R + r0 + tx] =
          f2b(tile[tx][ty + j * 8]);
  } else {  // rmsnorm path
    int row = bid - 10816;
    float4 v = ((const float4*)(x + (size_t)row * D_))[tid];
    float ss = v.x * v.x + v.y * v.y + v.z * v.z + v.w * v.w;
#pragma unroll
    for (int m = 1; m < 64; m <<= 1) ss += __shfl_xor(ss, m, 64);
    if ((tid & 63) == 0) tile[0][tid >> 6] = ss;
    __syncthreads();
    float tot = tile[0][0] + tile[0][1] + tile[0][2] + tile[0][3];
    float rs = rsqrtf(tot * (1.0f / D_) + 1e-6f);
    float4 wv = ((const float4*)w)[tid];
    ushort4 o;
    o.x = f2b(v.x * rs * wv.x); o.y = f2b(v.y * rs * wv.y);
    o.z = f2b(v.z * rs * wv.z); o.w = f2b(v.w * rs * wv.w);
    ((ushort4*)(out + (size_t)row * D_))[tid] = o;
  }
}

// ---------------- rmsnorm (fp32 in) -> bf16 out ----------------
__global__ void k_rmsnorm(const float* __restrict__ x, const float* __restrict__ w,
                          u16* __restrict__ out) {
  int row = blockIdx.x, tid = threadIdx.x;
  float4 v = ((const float4*)(x + (size_t)row * D_))[tid];
  float ss = v.x * v.x + v.y * v.y + v.z * v.z + v.w * v.w;
#pragma unroll
  for (int m = 1; m < 64; m <<= 1) ss += __shfl_xor(ss, m, 64);
  __shared__ float red[4];
  if ((tid & 63) == 0) red[tid >> 6] = ss;
  __syncthreads();
  float tot = red[0] + red[1] + red[2] + red[3];
  float rs = rsqrtf(tot * (1.0f / D_) + 1e-6f);
  float4 wv = ((const float4*)w)[tid];
  ushort4 o;
  o.x = f2b(v.x * rs * wv.x); o.y = f2b(v.y * rs * wv.y);
  o.z = f2b(v.z * rs * wv.z); o.w = f2b(v.w * rs * wv.w);
  ((ushort4*)(out + (size_t)row * D_))[tid] = o;
}

// ---------------- fused rope (q,k) + V transpose; one launch/layer ------------
// qkvb is the bf16 qkv GEMM output (r23: halves the fp32 round-trip traffic;
// RoPE on bf16-rounded q/k adds one quantization, ~0.2% rel, V path exact).
__global__ void k_ropev(const u16* __restrict__ qkvb, const float* __restrict__ cosT,
                        const float* __restrict__ sinT, u16* __restrict__ qh,
                        u16* __restrict__ kh, u16* __restrict__ vth) {
  __shared__ float tile[32][65];
  int bid = blockIdx.x;
  int tid = threadIdx.x;
  if (bid < BS_) {  // RoPE: q + k head-major
    int t = bid;
    int b = t >> 10, s = t & (S_ - 1);
    const u16* row = qkvb + (size_t)t * 1536;
    for (int p = tid; p < 512; p += 256) {           // q: 512 pairs
      int hh = p >> 5, d = p & 31;
      float x0 = b2f(row[hh * 64 + 2 * d]), x1 = b2f(row[hh * 64 + 2 * d + 1]);
      float c = cosT[s * 32 + d], sn = sinT[s * 32 + d];
      size_t o = ((size_t)(b * HQ_ + hh) * S_ + s) * HD_ + 2 * d;
      qh[o] = f2b(x0 * c - x1 * sn);
      qh[o + 1] = f2b(x0 * sn + x1 * c);
    }
    if (tid < 128) {                                  // k: 128 pairs
      int hh = tid >> 5, d = tid & 31;
      float x0 = b2f(row[1024 + hh * 64 + 2 * d]), x1 = b2f(row[1024 + hh * 64 + 2 * d + 1]);
      float c = cosT[s * 32 + d], sn = sinT[s * 32 + d];
      size_t o = ((size_t)(b * HKV_ + hh) * S_ + s) * HD_ + 2 * d;
      kh[o] = f2b(x0 * c - x1 * sn);
      kh[o + 1] = f2b(x0 * sn + x1 * c);
    }
  } else {  // V transpose -> vth [b][kvh][64][S] (bf16->f32->bf16 is exact)
    int v = bid - BS_;                // 0..255
    const int s0 = (v & 31) << 5, hh = (v >> 5) & 3, b = v >> 7;
    const int tx = tid & 63, ty = tid >> 6;  // load: 64 d x 4 s-rows
#pragma unroll
    for (int j = 0; j < 8; ++j) {
      int sl = j * 4 + ty;
      tile[sl][tx] = b2f(qkvb[(size_t)((b << 10) + s0 + sl) * 1536 + 1280 + hh * 64 + tx]);
    }
    __syncthreads();
    const int sx = tid & 31, dr = tid >> 5;  // store: 32 s x 8 d-rows
#pragma unroll
    for (int j = 0; j < 8; ++j) {
      int d = j * 8 + dr;
      vth[((size_t)((b * HKV_ + hh) << 6) + d) * S_ + s0 + sx] = f2b(tile[sx][d]);
    }
  }
}

// ---------------- 128x128 bf16 MFMA GEMM: C = A[M,*] @ BT[N,*]^T ----------------
// Depth-2 prefetch, 3-buffer rotation, counted vmcnt (r9/r10/r12 verified best).
// kdepth = K handled by this block (split-K via blockIdx.z); lda = row stride.
// EPI: 0 = f32 store, 2 = bf16 store, 4 = fp32 atomicAdd (split-K accumulate)
template <int EPI>
__global__ __launch_bounds__(256) void k_gemm(const u16* __restrict__ A,
                                              const u16* __restrict__ BT,
                                              void* __restrict__ Cp, int kdepth,
                                              int lda, int ldc) {
  __shared__ u16 As[3][4096];  // [8 blocks16][64 slots][8 u16] x 3 buffers
  __shared__ u16 Bs[3][4096];
  const int tid = threadIdx.x;
  const int lane = tid & 63, wid = tid >> 6;
  const int lin = blockIdx.y * 16 + blockIdx.x;
  const int cpx = (gridDim.x * gridDim.y) >> 3;
  const int swz = (lin & 7) * cpx + (lin >> 3);
  const int m0 = (swz & 15) << 7, n0 = (swz >> 4) << 7;
  const int wm = (wid >> 1) << 6, wn = (wid & 1) << 6;
  const int fr = lane & 15, fg = lane >> 4;

  f32x4 acc[4][4] = {};

  const int srow = (wid << 4) + (lane >> 2);
  const int scol = ((lane & 3) - ((lane >> 3) & 3)) & 3;
  const int kz = blockIdx.z * kdepth;
  const u16* ga = A + (size_t)(m0 + srow) * lda + kz + (scol << 3);
  const u16* gb = BT + (size_t)(n0 + srow) * lda + kz + (scol << 3);
  const int cb = wid << 9;  // wave-uniform LDS chunk base (u16 units)

  auto stage = [&](int buf, int k0) {
    u16* la = &As[buf][cb];
    u16* lb = &Bs[buf][cb];
    gload_lds16(ga + k0, la);
    gload_lds16(ga + (size_t)64 * lda + k0, la + 2048);
    gload_lds16(gb + k0, lb);
    gload_lds16(gb + (size_t)64 * lda + k0, lb + 2048);
  };

  const int nk = kdepth >> 5;
  stage(0, 0);
  stage(1, 32);

  const int ab = (wid >> 1) << 2, bb = (wid & 1) << 2;  // 16-row block bases
  const int foff = (fr << 5) + ((((fg + (fr >> 1)) & 3)) << 3);
  int cur = 0;
  for (int t = 0; t < nk; ++t) {
    if (t + 2 < nk) {
      int nb = cur + 2; if (nb >= 3) nb -= 3;
      stage(nb, (t + 2) << 5);
      asm volatile("s_waitcnt vmcnt(8)" ::: "memory");   // tile t retired; t+1,t+2 in flight
    } else if (t + 2 == nk) {
      asm volatile("s_waitcnt vmcnt(4)" ::: "memory");
    } else {
      asm volatile("s_waitcnt vmcnt(0)" ::: "memory");
    }
    __builtin_amdgcn_s_barrier();  // all waves' tile-t writes visible
    s16x8 af[4], bq[4];
#pragma unroll
    for (int i = 0; i < 4; ++i) {
      af[i] = *(const s16x8*)(&As[cur][((ab + i) << 9) + foff]);
      bq[i] = *(const s16x8*)(&Bs[cur][((bb + i) << 9) + foff]);
    }
#pragma unroll
    for (int mi = 0; mi < 4; ++mi)
#pragma unroll
      for (int ni = 0; ni < 4; ++ni)
        acc[mi][ni] = __builtin_amdgcn_mfma_f32_16x16x32_bf16(af[mi], bq[ni], acc[mi][ni], 0, 0, 0);
    __builtin_amdgcn_s_barrier();  // reads of buf(t) done before t+3 overwrites
    if (++cur == 3) cur = 0;
  }

#pragma unroll
  for (int mi = 0; mi < 4; ++mi) {
#pragma unroll
    for (int ni = 0; ni < 4; ++ni) {
#pragma unroll
      for (int r = 0; r < 4; ++r) {
        int row = m0 + wm + mi * 16 + fg * 4 + r;
        int col = n0 + wn + ni * 16 + fr;
        size_t off = (size_t)row * ldc + col;
        float v = acc[mi][ni][r];
        if (EPI == 0) ((float*)Cp)[off] = v;
        else if (EPI == 2) ((u16*)Cp)[off] = f2b(v);
        else atomicAdd((float*)Cp + off, v);
      }
    }
  }
}

// ---------------- 256x128 bf16 MFMA GEMM (big-N: lm_head, h13) ----------------
// 512 threads / 8 waves (4M x 2N, 64x64 out each): 16 waves/CU = 4 waves/SIMD.
// Depth-2 3-buffer counted-vmcnt schedule (r12 verified best); 3 loads/wave/stage.
// EPI: 0 = f32 store, 3 = fused SwiGLU (interleaved W13 pack; even lanes write
// silu(h1)*h3 bf16 to g, ldc = 2752).
template <int EPI>
__global__ __launch_bounds__(512, 4) void k_gemm2(const u16* __restrict__ A,
                                                  const u16* __restrict__ BT,
                                                  void* __restrict__ Cp, int K, int ldc) {
  __shared__ u16 As[3][8192];  // [16 blocks16][512 u16] x 3
  __shared__ u16 Bs[3][4096];  // [8 blocks16]
  const int tid = threadIdx.x;
  const int lane = tid & 63, wid = tid >> 6;  // 8 waves
  const int lin = blockIdx.y * gridDim.x + blockIdx.x;  // gridDim.x == 8
  const int cpx = (gridDim.x * gridDim.y) >> 3;
  const int swz = (lin & 7) * cpx + (lin >> 3);
  const int m0 = (swz & 7) << 8, n0 = (swz >> 3) << 7;
  const int fr = lane & 15, fg = lane >> 4;

  f32x4 acc[4][4] = {};

  const int srow = lane >> 2;  // 0..15 within a 16-row block
  const int scol = ((lane & 3) - ((lane >> 3) & 3)) & 3;
  // wave w stages A rows [32w,32w+32) -> blocks 2w,2w+1 ; B rows [16w,16w+16) -> block w
  const u16* ga = A + (size_t)(m0 + (wid << 5) + srow) * K + (scol << 3);
  const u16* gb = BT + (size_t)(n0 + (wid << 4) + srow) * K + (scol << 3);
  const int cba = wid << 10;  // 2 blocks * 512 u16
  const int cbb = wid << 9;   // 1 block * 512 u16

  auto stage = [&](int buf, int k0) {
    gload_lds16(ga + k0, &As[buf][cba]);
    gload_lds16(ga + (size_t)16 * K + k0, &As[buf][cba + 512]);
    gload_lds16(gb + k0, &Bs[buf][cbb]);
  };

  const int nk = K >> 5;
  stage(0, 0);
  stage(1, 32);

  const int am = (wid >> 1) << 2;  // A block base: wave M-group * 4
  const int bn = (wid & 1) << 2;   // B block base: wave N-group * 4
  const int foff = (fr << 5) + ((((fg + (fr >> 1)) & 3)) << 3);
  int cur = 0;
  for (int t = 0; t < nk; ++t) {
    if (t + 2 < nk) {
      int nb = cur + 2; if (nb >= 3) nb -= 3;
      stage(nb, (t + 2) << 5);
      asm volatile("s_waitcnt vmcnt(6)" ::: "memory");  // tile t retired; t+1,t+2 in flight
    } else if (t + 2 == nk) {
      asm volatile("s_waitcnt vmcnt(3)" ::: "memory");
    } else {
      asm volatile("s_waitcnt vmcnt(0)" ::: "memory");
    }
    __builtin_amdgcn_s_barrier();
    s16x8 af[4], bq[4];
#pragma unroll
    for (int i = 0; i < 4; ++i) {
      af[i] = *(const s16x8*)(&As[cur][((am + i) << 9) + foff]);
      bq[i] = *(const s16x8*)(&Bs[cur][((bn + i) << 9) + foff]);
    }
#pragma unroll
    for (int mi = 0; mi < 4; ++mi)
#pragma unroll
      for (int ni = 0; ni < 4; ++ni)
        acc[mi][ni] = __builtin_amdgcn_mfma_f32_16x16x32_bf16(af[mi], bq[ni], acc[mi][ni], 0, 0, 0);
    __builtin_amdgcn_s_barrier();
    if (++cur == 3) cur = 0;
  }

#pragma unroll
  for (int mi = 0; mi < 4; ++mi) {
#pragma unroll
    for (int ni = 0; ni < 4; ++ni) {
#pragma unroll
      for (int r = 0; r < 4; ++r) {
        int row = m0 + ((wid >> 1) << 6) + mi * 16 + fg * 4 + r;
        int col = n0 + ((wid & 1) << 6) + ni * 16 + fr;
        float v = acc[mi][ni][r];
        if (EPI == 0) {
          ((float*)Cp)[(size_t)row * ldc + col] = v;
        } else {  // EPI == 3: fused SwiGLU
          float o = __shfl_xor(v, 1, 64);  // partner col (h1<->h3)
          if (!(fr & 1)) {
            float s = v / (1.0f + __expf(-v)) * o;
            ((u16*)Cp)[(size_t)row * ldc + (col >> 1)] = f2b(s);
          }
        }
      }
    }
  }
}

// ---------------- flash attention: 1 wave = 16 q-rows, KV tiles of 32 -----------
__global__ __launch_bounds__(256) void k_attn(const u16* __restrict__ qh,
                                              const u16* __restrict__ kh,
                                              const u16* __restrict__ vth,
                                              u16* __restrict__ attno, int isGlobal) {
  __shared__ u16 pb[4][512];  // per-wave P tile [16][32]
  const int qblk = blockIdx.x, hq = blockIdx.y, b = blockIdx.z;
  const int lane = threadIdx.x & 63, wid = threadIdx.x >> 6;
  const int fr = lane & 15, fg = lane >> 4;
  const int q0 = (qblk << 6) + (wid << 4);
  const int hk = hq >> 2;  // GQA: 4 q-heads per kv-head
  const u16* Q = qh + ((size_t)(b * HQ_ + hq) * S_) * HD_;
  const u16* Kh = kh + ((size_t)(b * HKV_ + hk) * S_) * HD_;
  const u16* VT = vth + ((size_t)(b * HKV_ + hk) * HD_) * S_;
  u16* pbuf = pb[wid];

  const s16x8 aq0 = *(const s16x8*)(Q + (q0 + fr) * HD_ + fg * 8);
  const s16x8 aq1 = *(const s16x8*)(Q + (q0 + fr) * HD_ + 32 + fg * 8);

  f32x4 o0 = {}, o1 = {}, o2 = {}, o3 = {};
  float m[4], l[4];
#pragma unroll
  for (int r = 0; r < 4; ++r) { m[r] = -1e30f; l[r] = 0.0f; }

  int kt0 = 0;
  if (!isGlobal) { int lo = q0 - (WINDOW_ - 1); if (lo > 0) kt0 = lo & ~31; }
  const int ktend = q0 + 16;

  for (int kt = kt0; kt < ktend; kt += 32) {
    // QK^T: scores [16 q][32 k] in two 16x16 accumulators
    f32x4 sc0 = {}, sc1 = {};
    {
      s16x8 b0 = *(const s16x8*)(Kh + (kt + fr) * HD_ + fg * 8);
      s16x8 b1 = *(const s16x8*)(Kh + (kt + fr) * HD_ + 32 + fg * 8);
      sc0 = __builtin_amdgcn_mfma_f32_16x16x32_bf16(aq0, b0, sc0, 0, 0, 0);
      sc0 = __builtin_amdgcn_mfma_f32_16x16x32_bf16(aq1, b1, sc0, 0, 0, 0);
      s16x8 c0 = *(const s16x8*)(Kh + (kt + 16 + fr) * HD_ + fg * 8);
      s16x8 c1 = *(const s16x8*)(Kh + (kt + 16 + fr) * HD_ + 32 + fg * 8);
      sc1 = __builtin_amdgcn_mfma_f32_16x16x32_bf16(aq0, c0, sc1, 0, 0, 0);
      sc1 = __builtin_amdgcn_mfma_f32_16x16x32_bf16(aq1, c1, sc1, 0, 0, 0);
    }
#pragma unroll
    for (int r = 0; r < 4; ++r) {
      int row = q0 + fg * 4 + r;
      int col0 = kt + fr, col1 = kt + 16 + fr;
      bool v0 = (col0 <= row) && (isGlobal || (row - col0) < WINDOW_);
      bool v1 = (col1 <= row) && (isGlobal || (row - col1) < WINDOW_);
      float s0 = v0 ? sc0[r] * 0.125f : -1e30f;
      float s1 = v1 ? sc1[r] * 0.125f : -1e30f;
      float t = fmaxf(s0, s1);
#pragma unroll
      for (int msk = 1; msk < 16; msk <<= 1) t = fmaxf(t, __shfl_xor(t, msk, 16));
      float mn = fmaxf(m[r], t);
      float fsc = __expf(m[r] - mn);  // -1e30 sentinel keeps this finite (exp(0)=1)
      m[r] = mn;
      float p0 = v0 ? __expf(s0 - mn) : 0.0f;  // mask by select, never by exp(-inf)
      float p1 = v1 ? __expf(s1 - mn) : 0.0f;
      float ps = p0 + p1;
#pragma unroll
      for (int msk = 1; msk < 16; msk <<= 1) ps += __shfl_xor(ps, msk, 16);
      l[r] = l[r] * fsc + ps;
      o0[r] *= fsc; o1[r] *= fsc; o2[r] *= fsc; o3[r] *= fsc;
      pbuf[(fg * 4 + r) * 32 + fr] = f2b(p0);
      pbuf[(fg * 4 + r) * 32 + 16 + fr] = f2b(p1);
    }
    // PV: P (from per-wave LDS, A-fragment layout) x V^T rows
    s16x8 ap = *(const s16x8*)(pbuf + fr * 32 + fg * 8);
    {
      s16x8 bv0 = *(const s16x8*)(VT + (size_t)(0 + fr) * S_ + kt + fg * 8);
      o0 = __builtin_amdgcn_mfma_f32_16x16x32_bf16(ap, bv0, o0, 0, 0, 0);
      s16x8 bv1 = *(const s16x8*)(VT + (size_t)(16 + fr) * S_ + kt + fg * 8);
      o1 = __builtin_amdgcn_mfma_f32_16x16x32_bf16(ap, bv1, o1, 0, 0, 0);
      s16x8 bv2 = *(const s16x8*)(VT + (size_t)(32 + fr) * S_ + kt + fg * 8);
      o2 = __builtin_amdgcn_mfma_f32_16x16x32_bf16(ap, bv2, o2, 0, 0, 0);
      s16x8 bv3 = *(const s16x8*)(VT + (size_t)(48 + fr) * S_ + kt + fg * 8);
      o3 = __builtin_amdgcn_mfma_f32_16x16x32_bf16(ap, bv3, o3, 0, 0, 0);
    }
  }

#pragma unroll
  for (int r = 0; r < 4; ++r) {
    int row = q0 + fg * 4 + r;
    float inv = 1.0f / l[r];
    size_t base = ((size_t)b * S_ + row) * (HQ_ * HD_) + hq * HD_;
    attno[base + fr] = f2b(o0[r] * inv);
    attno[base + 16 + fr] = f2b(o1[r] * inv);
    attno[base + 32 + fr] = f2b(o2[r] * inv);
    attno[base + 48 + fr] = f2b(o3[r] * inv);
  }
}

extern "C" void kernel_launch(void* const* d_in, const int* in_sizes, int n_in,
                              void* d_out, int out_size, void* d_ws, size_t ws_size,
                              hipStream_t stream) {
  (void)in_sizes; (void)n_in; (void)out_size; (void)ws_size;
  const int* idx = (const int*)d_in[0];
  const float* emb = (const float*)d_in[1];
  const float* Wq = (const float*)d_in[2];
  const float* Wk = (const float*)d_in[3];
  const float* Wv = (const float*)d_in[4];
  const float* Wo = (const float*)d_in[5];
  const float* w1 = (const float*)d_in[6];
  const float* w3 = (const float*)d_in[7];
  const float* w2 = (const float*)d_in[8];
  const float* n1 = (const float*)d_in[9];
  const float* n2 = (const float*)d_in[10];
  const float* nf = (const float*)d_in[11];
  float* out = (float*)d_out;

  char* p = (char*)d_ws;
  auto carve = [&](size_t bytes) {
    char* q = p;
    p += (bytes + 255) & ~(size_t)255;
    return (void*)q;
  };
  float* x = (float*)carve((size_t)BS_ * D_ * 4);
  u16* h = (u16*)carve((size_t)BS_ * D_ * 2);
  u16* qkvb = (u16*)carve((size_t)BS_ * 1536 * 2);
  u16* qh = (u16*)carve((size_t)B_ * HQ_ * S_ * HD_ * 2);
  u16* khb = (u16*)carve((size_t)B_ * HKV_ * S_ * HD_ * 2);
  u16* vth = (u16*)carve((size_t)B_ * HKV_ * HD_ * S_ * 2);
  u16* attno = (u16*)carve((size_t)BS_ * D_ * 2);
  u16* g = (u16*)carve((size_t)BS_ * H_ * 2);
  u16* wT = (u16*)carve((size_t)11075584 * 2);
  float* cosT = (float*)carve((size_t)S_ * 32 * 4);
  float* sinT = (float*)carve((size_t)S_ * 32 * 4);
  u16* embb = (u16*)carve((size_t)V_ * D_ * 2);

  // startup: emb->bf16, rope tables, token-embedding gather (single launch)
  k_init<<<32000 + 128 + BS_, 256, 0, stream>>>(emb, embb, cosT, sinT, idx, x);

  for (int l = 0; l < L_; ++l) {
    T7 t7;
    t7.m[0] = { Wq + (size_t)l * D_ * 1024, wT, D_, 1024, 0, 1, 0 };
    t7.m[1] = { Wk + (size_t)l * D_ * 256, wT + 1048576, D_, 256, 1024, 1, 0 };
    t7.m[2] = { Wv + (size_t)l * D_ * 256, wT + 1310720, D_, 256, 1280, 1, 0 };
    t7.m[3] = { Wo + (size_t)l * 1024 * D_, wT + 1572864, 1024, D_, 1536, 1, 0 };
    // W1/W3 interleaved: w1 col j -> row 2j, w3 col j -> row 2j+1 (fused silu)
    t7.m[4] = { w1 + (size_t)l * D_ * H_, wT + 2621440, D_, H_, 2560, 2, 0 };
    t7.m[5] = { w3 + (size_t)l * D_ * H_, wT + 2621440, D_, H_, 5312, 2, 1 };
    t7.m[6] = { w2 + (size_t)l * H_ * D_, wT + 8257536, H_, D_, 8064, 1, 0 };

    // fused: weight pack transpose + rmsnorm1 (one launch)
    k_tr_rms<<<10816 + BS_, 256, 0, stream>>>(t7, x, n1 + (size_t)l * D_, h);
    // QKV fused: BT = [WqT; WkT; WvT] (N=1536), bf16 out (r23)
    k_gemm<2><<<dim3(16, 12), 256, 0, stream>>>(h, wT, qkvb, 1024, 1024, 1536);
    k_ropev<<<BS_ + 256, 256, 0, stream>>>(qkvb, cosT, sinT, qh, khb, vth);
    int ig = ((l + 1) % 4) == 0;
    k_attn<<<dim3(16, HQ_, B_), 256, 0, stream>>>(qh, khb, vth, attno, ig);
    // x += attno @ Wo  (split-K=2, fp32 atomic accumulate into residual)
    k_gemm<4><<<dim3(16, 8, 2), 256, 0, stream>>>(attno, wT + 1572864, x, 512, 1024, 1024);
    k_rmsnorm<<<BS_, 256, 0, stream>>>(x, n2 + (size_t)l * D_, h);
    // g = silu(h@W1) * (h@W3), fused: interleaved W13 pack, 256x128 tiles
    k_gemm2<3><<<dim3(8, 43), 512, 0, stream>>>(h, wT + 2621440, g, 1024, 2752);
    // x += g @ W2  (split-K=2 atomic)
    k_gemm<4><<<dim3(16, 8, 2), 256, 0, stream>>>(g, wT + 8257536, x, 1376, 2752, 1024);
  }

  k_rmsnorm<<<BS_, 256, 0, stream>>>(x, nf, h);
  // logits = xn @ emb^T  (BT = emb bf16), 256x128 tiles
  k_gemm2<0><<<dim3(8, 250), 512, 0, stream>>>(h, embb, out, 1024, 32000);
}